// Round 4
// baseline (869.073 us; speedup 1.0000x reference)
//
#include <hip/hip_runtime.h>
#include <math.h>

#define BB 8
#define CCH 36
#define HH 256
#define WW 256
#define EE 6
#define TDIM 32
#define HID 72
// ws layout: floats [0,288) avg; [288,576) max; [576,624) gates.
// bytes: wt1 (bf16) at 4096, size 6*3*80*128*2 = 368640; wt2 at 372736, size 6*3*48*224*2 = 387072.
#define WS_GATES (BB*CCH*2)
#define WT1_OFF 4096
#define WT2_OFF (4096 + 368640)

typedef __attribute__((ext_vector_type(8))) short bf16x8;
typedef __attribute__((ext_vector_type(4))) float f32x4;
typedef __attribute__((ext_vector_type(4))) short short4v;

static __device__ __forceinline__ unsigned short f2bf(float f) {
  union { float f; unsigned u; } v; v.f = f;
  unsigned r = v.u + 0x7FFF + ((v.u >> 16) & 1);
  return (unsigned short)(r >> 16);
}
// tanh-form GELU: 0.5x(1+tanh(0.79788456(x+0.044715x^3))) = x*e/(e+1), e=exp(2u).
// |gelu_tanh - gelu_erf| <= ~3e-4, far under bf16 noise. Clamped: no inf/NaN.
static __device__ __forceinline__ float gelu_fast(float x) {
  float u2 = x * (1.5957691216f + 0.0713548162f * x * x);   // 2u
  u2 = fminf(fmaxf(u2, -30.f), 30.f);
  float e = __expf(u2);
  return x * e * __builtin_amdgcn_rcpf(e + 1.f);
}

// ---------------- Kernel 1: avg+max pool ----------------
__global__ __launch_bounds__(256) void pool_kernel(const float* __restrict__ x,
                                                   float* __restrict__ ws) {
  const int bc = blockIdx.x;
  const float* p = x + (size_t)bc * (HH * WW);
  float s = 0.f, m = -INFINITY;
  for (int i = threadIdx.x; i < (HH * WW) / 4; i += 256) {
    float4 v = ((const float4*)p)[i];
    s += v.x + v.y + v.z + v.w;
    m = fmaxf(m, fmaxf(fmaxf(v.x, v.y), fmaxf(v.z, v.w)));
  }
  for (int off = 32; off; off >>= 1) {
    s += __shfl_down(s, off);
    m = fmaxf(m, __shfl_down(m, off));
  }
  __shared__ float ss[4], sm[4];
  int wid = threadIdx.x >> 6, lane = threadIdx.x & 63;
  if (lane == 0) { ss[wid] = s; sm[wid] = m; }
  __syncthreads();
  if (threadIdx.x == 0) {
    float S = ss[0] + ss[1] + ss[2] + ss[3];
    float M = fmaxf(fmaxf(sm[0], sm[1]), fmaxf(sm[2], sm[3]));
    ws[bc] = S * (1.f / (HH * WW));
    ws[BB * CCH + bc] = M;
  }
}

// ---------------- Kernel 2: gating MLP + top-2 + loss ----------------
__global__ void gate_kernel(const float* __restrict__ time,
                            const float* __restrict__ time_w,
                            const float* __restrict__ time_b,
                            const float* __restrict__ w1, const float* __restrict__ b1,
                            const float* __restrict__ w2, const float* __restrict__ b2,
                            float* __restrict__ ws, float* __restrict__ loss_out) {
  __shared__ float v[BB * HID];
  __shared__ float h[BB * HID];
  __shared__ float logits[BB * EE];
  const int t = threadIdx.x;
  const float* avg = ws;
  const float* mx = ws + BB * CCH;
  for (int i = t; i < BB * HID; i += blockDim.x) {
    int b = i / HID, c = i % HID;
    float base = (c < CCH) ? avg[b * CCH + c] : mx[b * CCH + (c - CCH)];
    float acc = time_b[c];
    for (int k = 0; k < TDIM; k++) acc += time[b * TDIM + k] * time_w[k * HID + c];
    v[i] = base + acc;
  }
  __syncthreads();
  for (int i = t; i < BB * HID; i += blockDim.x) {
    int b = i / HID, c = i % HID;
    float acc = b1[c];
    for (int k = 0; k < HID; k++) acc += v[b * HID + k] * w1[k * HID + c];
    h[i] = acc > 0.f ? acc : 0.01f * acc;
  }
  __syncthreads();
  for (int i = t; i < BB * EE; i += blockDim.x) {
    int b = i / EE, e = i % EE;
    float acc = b2[e];
    for (int k = 0; k < HID; k++) acc += h[b * HID + k] * w2[k * EE + e];
    logits[i] = acc;
  }
  __syncthreads();
  if (t == 0) {
    float imp[EE], ld[EE];
    for (int e = 0; e < EE; e++) { imp[e] = 0.f; ld[e] = 0.f; }
    for (int b = 0; b < BB; b++) {
      int i1 = -1, i2 = -1;
      float v1 = -1e30f, v2 = -1e30f;
      for (int e = 0; e < EE; e++) {
        float lv = logits[b * EE + e];
        if (lv > v1) { v2 = v1; i2 = i1; v1 = lv; i1 = e; }
        else if (lv > v2) { v2 = lv; i2 = e; }
      }
      float e2 = expf(v2 - v1);
      float g1 = 1.f / (1.f + e2), g2 = e2 / (1.f + e2);
      for (int e = 0; e < EE; e++) ws[WS_GATES + b * EE + e] = 0.f;
      ws[WS_GATES + b * EE + i1] = g1;
      ws[WS_GATES + b * EE + i2] = g2;
      imp[i1] += g1; imp[i2] += g2;
      ld[i1] += 1.f; ld[i2] += 1.f;
    }
    float loss = 0.f;
    {
      float m = 0.f; for (int e = 0; e < EE; e++) m += imp[e]; m /= EE;
      float var = 0.f; for (int e = 0; e < EE; e++) { float d = imp[e] - m; var += d * d; }
      var /= (EE - 1);
      loss += var / (m * m + 1e-10f);
      m = 0.f; for (int e = 0; e < EE; e++) m += ld[e]; m /= EE;
      var = 0.f; for (int e = 0; e < EE; e++) { float d = ld[e] - m; var += d * d; }
      var /= (EE - 1);
      loss += var / (m * m + 1e-10f);
    }
    loss_out[0] = 0.01f * loss;
  }
}

// ---------------- Kernel 2.5: weight transform to [e][dx][co][k] bf16 ----------------
// conv1: k = dy*40 + ci  (K=120 used, padded 128; pad rows are ZERO), co 72->80
// conv2: k = dy*72 + ci  (K=216 used, padded 224; pad ZERO), co 36->48
__global__ __launch_bounds__(256) void wxform_kernel(const float* __restrict__ w1,
                                                     const float* __restrict__ w2,
                                                     unsigned short* __restrict__ wt1,
                                                     unsigned short* __restrict__ wt2) {
  int i = blockIdx.x * 256 + threadIdx.x;
  const int n1 = EE * 3 * 80 * 128;
  if (i < n1) {
    int k = i & 127;
    int t = i >> 7;
    int co = t % 80; t /= 80;
    int dx = t % 3;  int e = t / 3;
    int dy = k / 40, ci = k - dy * 40;
    float v = 0.f;
    if (co < HID && dy < 3 && ci < CCH)
      v = w1[((((size_t)e * HID + co) * CCH + ci) * 3 + dy) * 3 + dx];
    wt1[i] = f2bf(v);
  }
  const int n2 = EE * 3 * 48 * 224;
  if (i < n2) {
    int k = i % 224;
    int t = i / 224;
    int co = t % 48; t /= 48;
    int dx = t % 3;  int e = t / 3;
    int dy = k / 72, ci = k - dy * 72;
    float v = 0.f;
    if (co < CCH && dy < 3)
      v = w2[((((size_t)e * CCH + co) * HID + ci) * 3 + dy) * 3 + dx];
    wt2[i] = f2bf(v);
  }
}

// ---------------- Kernel 3: fused MFMA conv1+GELU+conv2 ----------------
// Tile: 32 wide x 2 tall. xs: [6][36][40] bf16 ch-minor; ts: [4][34][72] bf16.
// Weight A-fragments are read DIRECTLY from global (L1-resident 20KB slabs,
// identical addresses across waves) -> no weight LDS, no staging barriers.
#define XRR 6
#define XCC 36
#define CIP 40
#define TCC 34
__global__ __launch_bounds__(256, 4) void conv_kernel(
    const float* __restrict__ x,
    const unsigned short* __restrict__ wt1,
    const unsigned short* __restrict__ wt2,
    const float* __restrict__ wsg,
    float* __restrict__ y) {
  __shared__ __align__(16) char lds[36864];
  char* xsB = lds;            // 17280 B
  char* tsB = lds + 17280;    // 19584 B

  const int tid = threadIdx.x;
  const int w = tid >> 6;
  const int lane = tid & 63;
  const int l15 = lane & 15;
  const int kl = lane >> 4;
  const int tileId = blockIdx.x;
  const int b = blockIdx.y;
  const int tx0 = (tileId & 7) * 32;
  const int ty0 = (tileId >> 3) * 2;
  const size_t xbase = (size_t)b * (CCH * HH * WW);

  // ---- stage x tile (f32 -> bf16, ch-minor) ----
  for (int i = tid; i < XRR * XCC * CIP; i += 256) {
    int xc = i % XCC;
    int t2 = i / XCC;
    int xr = t2 % XRR;
    int ci = t2 / XRR;
    int gy = ty0 - 2 + xr, gx = tx0 - 2 + xc;
    float v = 0.f;
    if (ci < CCH && (unsigned)gy < (unsigned)HH && (unsigned)gx < (unsigned)WW)
      v = x[xbase + ((size_t)ci << 16) + (size_t)(gy * WW + gx)];
    *(unsigned short*)(xsB + 2 * ((xr * XCC + xc) * CIP + ci)) = f2bf(v);
  }

  // ---- per-lane K-chunk byte-offset tables (B side) ----
  int xkoff[4];   // conv1: (dy*XCC*CIP + ci)*2, or -1 if k>=120
#pragma unroll
  for (int kc = 0; kc < 4; kc++) {
    int k0 = kc * 32 + kl * 8;
    int d = (k0 >= 80) ? 2 : (k0 >= 40 ? 1 : 0);
    xkoff[kc] = (k0 < 120) ? (d * XCC * CIP + (k0 - 40 * d)) * 2 : -1;
  }
  int tkoff[7];   // conv2: (dy*TCC*HID + ci)*2, or -1 if k>=216
#pragma unroll
  for (int kc = 0; kc < 7; kc++) {
    int k0 = kc * 32 + kl * 8;
    int d = (k0 >= 144) ? 2 : (k0 >= 72 ? 1 : 0);
    tkoff[kc] = (k0 < 216) ? (d * TCC * HID + (k0 - 72 * d)) * 2 : -1;
  }

  // ---- conv1 pixel coords (T grid 4x34=136px, 9 N-slots; wave w: slots w,w+4,w+8) ----
  const int nslot = (w == 0) ? 3 : 2;
  int pbase1[3], vimg[3], pst[3], trA[3], tcA[3];
#pragma unroll
  for (int i = 0; i < 3; i++) {
    int p = (w + 4 * i) * 16 + l15;
    int pr = p / 34;
    int tc = p - pr * 34;
    int prc = pr < 3 ? pr : 3;
    trA[i] = prc; tcA[i] = tc;
    pbase1[i] = (prc * XCC + tc) * CIP * 2;
    int gy = ty0 - 1 + pr, gx = tx0 - 1 + tc;
    pst[i] = (pr < 4) ? 1 : 0;
    vimg[i] = (pr < 4 && (unsigned)gy < (unsigned)HH && (unsigned)gx < (unsigned)WW) ? 1 : 0;
  }
  // conv2 pixel coords (2x32=64px, wave w owns N-slot w)
  const int p2 = w * 16 + l15;
  const int or2 = p2 >> 5, oc2 = p2 & 31;
  const int pbase2 = (or2 * TCC + oc2) * HID * 2;

  // per-lane A-fragment element offsets
  const int aoff1 = l15 * 128 + kl * 8;
  const int aoff2 = l15 * 224 + kl * 8;

  f32x4 yacc[3];
#pragma unroll
  for (int mt = 0; mt < 3; mt++) yacc[mt] = (f32x4){0.f, 0.f, 0.f, 0.f};

  __syncthreads();

  for (int e = 0; e < EE; e++) {
    const float gv = wsg[b * EE + e];
    if (gv == 0.f) continue;
    __syncthreads();   // previous expert's conv2 done reading ts

    // ================= conv1 (A from global, B from xs LDS) =================
    f32x4 acc[3][5];
#pragma unroll
    for (int i = 0; i < 3; i++)
#pragma unroll
      for (int mt = 0; mt < 5; mt++) acc[i][mt] = (f32x4){0.f, 0.f, 0.f, 0.f};

    const unsigned short* w1e = wt1 + (size_t)e * (3 * 80 * 128) + aoff1;
#pragma unroll
    for (int dx = 0; dx < 3; dx++) {
#pragma unroll
      for (int kc = 0; kc < 4; kc++) {
        bf16x8 bv[3];
#pragma unroll
        for (int i = 0; i < 3; i++) {
          if (i < nslot) {
            int ba = (xkoff[kc] >= 0) ? (pbase1[i] + xkoff[kc] + dx * (CIP * 2)) : 0;
            bv[i] = *(const bf16x8*)(xsB + ba);
          }
        }
#pragma unroll
        for (int mt = 0; mt < 5; mt++) {
          bf16x8 av = *(const bf16x8*)(w1e + dx * 10240 + mt * 2048 + kc * 32);
#pragma unroll
          for (int i = 0; i < 3; i++)
            if (i < nslot)
              acc[i][mt] = __builtin_amdgcn_mfma_f32_16x16x32_bf16(av, bv[i], acc[i][mt], 0, 0, 0);
        }
      }
    }

    // ---- GELU + store T (bf16, ch-minor; exact 0 outside image) ----
#pragma unroll
    for (int i = 0; i < 3; i++) {
      if (i < nslot) {
#pragma unroll
        for (int mt = 0; mt < 5; mt++) {
          int co0 = mt * 16 + kl * 4;
          if (co0 < HID && pst[i]) {
            short4v pk;
            float v0 = vimg[i] ? gelu_fast(acc[i][mt].x) : 0.f;
            float v1 = vimg[i] ? gelu_fast(acc[i][mt].y) : 0.f;
            float v2 = vimg[i] ? gelu_fast(acc[i][mt].z) : 0.f;
            float v3 = vimg[i] ? gelu_fast(acc[i][mt].w) : 0.f;
            pk.x = (short)f2bf(v0); pk.y = (short)f2bf(v1);
            pk.z = (short)f2bf(v2); pk.w = (short)f2bf(v3);
            *(short4v*)(tsB + ((trA[i] * TCC + tcA[i]) * HID + co0) * 2) = pk;
          }
        }
      }
    }
    __syncthreads();

    // ================= conv2 (A from global, B from ts LDS) =================
    f32x4 acc2[3];
#pragma unroll
    for (int mt = 0; mt < 3; mt++) acc2[mt] = (f32x4){0.f, 0.f, 0.f, 0.f};

    const unsigned short* w2e = wt2 + (size_t)e * (3 * 48 * 224) + aoff2;
#pragma unroll
    for (int dx = 0; dx < 3; dx++) {
#pragma unroll
      for (int kc = 0; kc < 7; kc++) {
        int ba = (tkoff[kc] >= 0) ? (pbase2 + tkoff[kc] + dx * (HID * 2)) : 0;
        bf16x8 bv = *(const bf16x8*)(tsB + ba);
#pragma unroll
        for (int mt = 0; mt < 3; mt++) {
          bf16x8 av = *(const bf16x8*)(w2e + dx * 10752 + mt * 3584 + kc * 32);
          acc2[mt] = __builtin_amdgcn_mfma_f32_16x16x32_bf16(av, bv, acc2[mt], 0, 0, 0);
        }
      }
    }
#pragma unroll
    for (int mt = 0; mt < 3; mt++) yacc[mt] += gv * acc2[mt];
  }

  // ---- store y (f32) ----
#pragma unroll
  for (int mt = 0; mt < 3; mt++) {
#pragma unroll
    for (int r = 0; r < 4; r++) {
      int co = mt * 16 + kl * 4 + r;
      if (co < CCH) {
        float v = (r == 0) ? yacc[mt].x : (r == 1) ? yacc[mt].y : (r == 2) ? yacc[mt].z : yacc[mt].w;
        y[xbase + ((size_t)co << 16) + (size_t)((ty0 + or2) * WW + tx0 + oc2)] = v;
      }
    }
  }
}

extern "C" void kernel_launch(void* const* d_in, const int* in_sizes, int n_in,
                              void* d_out, int out_size, void* d_ws, size_t ws_size,
                              hipStream_t stream) {
  const float* x      = (const float*)d_in[0];
  const float* time   = (const float*)d_in[1];
  const float* time_w = (const float*)d_in[2];
  const float* time_b = (const float*)d_in[3];
  const float* gw1    = (const float*)d_in[4];
  const float* gb1    = (const float*)d_in[5];
  const float* gw2    = (const float*)d_in[6];
  const float* gb2    = (const float*)d_in[7];
  const float* w1     = (const float*)d_in[8];
  const float* w2     = (const float*)d_in[9];
  float* out = (float*)d_out;
  float* ws  = (float*)d_ws;
  unsigned short* wt1 = (unsigned short*)((char*)d_ws + WT1_OFF);
  unsigned short* wt2 = (unsigned short*)((char*)d_ws + WT2_OFF);

  hipLaunchKernelGGL(pool_kernel, dim3(BB * CCH), dim3(256), 0, stream, x, ws);
  hipLaunchKernelGGL(gate_kernel, dim3(1), dim3(128), 0, stream,
                     time, time_w, time_b, gw1, gb1, gw2, gb2,
                     ws, out + (size_t)(out_size - 1));
  hipLaunchKernelGGL(wxform_kernel, dim3(756), dim3(256), 0, stream, w1, w2, wt1, wt2);
  hipLaunchKernelGGL(conv_kernel, dim3(1024, BB), dim3(256), 0, stream,
                     x, wt1, wt2, ws + WS_GATES, out);
}

// Round 5
// 595.518 us; speedup vs baseline: 1.4594x; 1.4594x over previous
//
#include <hip/hip_runtime.h>
#include <math.h>

#define BB 8
#define CCH 36
#define HH 256
#define WW 256
#define EE 6
#define TDIM 32
#define HID 72
// ws layout: floats [0,288) avg; [288,576) max; [576,624) gates.
// bytes: wt1 frags at 4096 (360 frags x 1024B = 368640); wt2 frags at 372736 (378 x 1024 = 387072).
#define WS_GATES (BB*CCH*2)
#define WT1_OFF 4096
#define WT2_OFF (4096 + 368640)

typedef __attribute__((ext_vector_type(8))) short bf16x8;
typedef __attribute__((ext_vector_type(4))) float f32x4;
typedef __attribute__((ext_vector_type(4))) short short4v;

static __device__ __forceinline__ unsigned short f2bf(float f) {
  union { float f; unsigned u; } v; v.f = f;
  unsigned r = v.u + 0x7FFF + ((v.u >> 16) & 1);
  return (unsigned short)(r >> 16);
}
// tanh-form GELU = x*e/(e+1), e=exp(2u), 2u = 1.59577x + 0.0713548x^3. |err| ~3e-4.
static __device__ __forceinline__ float gelu_fast(float x) {
  float u2 = x * (1.5957691216f + 0.0713548162f * x * x);
  u2 = fminf(fmaxf(u2, -30.f), 30.f);
  float e = __expf(u2);
  return x * e * __builtin_amdgcn_rcpf(e + 1.f);
}

// ---------------- Kernel 1: avg+max pool ----------------
__global__ __launch_bounds__(256) void pool_kernel(const float* __restrict__ x,
                                                   float* __restrict__ ws) {
  const int bc = blockIdx.x;
  const float* p = x + (size_t)bc * (HH * WW);
  float s = 0.f, m = -INFINITY;
  for (int i = threadIdx.x; i < (HH * WW) / 4; i += 256) {
    float4 v = ((const float4*)p)[i];
    s += v.x + v.y + v.z + v.w;
    m = fmaxf(m, fmaxf(fmaxf(v.x, v.y), fmaxf(v.z, v.w)));
  }
  for (int off = 32; off; off >>= 1) {
    s += __shfl_down(s, off);
    m = fmaxf(m, __shfl_down(m, off));
  }
  __shared__ float ss[4], sm[4];
  int wid = threadIdx.x >> 6, lane = threadIdx.x & 63;
  if (lane == 0) { ss[wid] = s; sm[wid] = m; }
  __syncthreads();
  if (threadIdx.x == 0) {
    float S = ss[0] + ss[1] + ss[2] + ss[3];
    float M = fmaxf(fmaxf(sm[0], sm[1]), fmaxf(sm[2], sm[3]));
    ws[bc] = S * (1.f / (HH * WW));
    ws[BB * CCH + bc] = M;
  }
}

// ---------------- Kernel 2: gating MLP + top-2 + loss ----------------
__global__ void gate_kernel(const float* __restrict__ time,
                            const float* __restrict__ time_w,
                            const float* __restrict__ time_b,
                            const float* __restrict__ w1, const float* __restrict__ b1,
                            const float* __restrict__ w2, const float* __restrict__ b2,
                            float* __restrict__ ws, float* __restrict__ loss_out) {
  __shared__ float v[BB * HID];
  __shared__ float h[BB * HID];
  __shared__ float logits[BB * EE];
  const int t = threadIdx.x;
  const float* avg = ws;
  const float* mx = ws + BB * CCH;
  for (int i = t; i < BB * HID; i += blockDim.x) {
    int b = i / HID, c = i % HID;
    float base = (c < CCH) ? avg[b * CCH + c] : mx[b * CCH + (c - CCH)];
    float acc = time_b[c];
    for (int k = 0; k < TDIM; k++) acc += time[b * TDIM + k] * time_w[k * HID + c];
    v[i] = base + acc;
  }
  __syncthreads();
  for (int i = t; i < BB * HID; i += blockDim.x) {
    int b = i / HID, c = i % HID;
    float acc = b1[c];
    for (int k = 0; k < HID; k++) acc += v[b * HID + k] * w1[k * HID + c];
    h[i] = acc > 0.f ? acc : 0.01f * acc;
  }
  __syncthreads();
  for (int i = t; i < BB * EE; i += blockDim.x) {
    int b = i / EE, e = i % EE;
    float acc = b2[e];
    for (int k = 0; k < HID; k++) acc += h[b * HID + k] * w2[k * EE + e];
    logits[i] = acc;
  }
  __syncthreads();
  if (t == 0) {
    float imp[EE], ld[EE];
    for (int e = 0; e < EE; e++) { imp[e] = 0.f; ld[e] = 0.f; }
    for (int b = 0; b < BB; b++) {
      int i1 = -1, i2 = -1;
      float v1 = -1e30f, v2 = -1e30f;
      for (int e = 0; e < EE; e++) {
        float lv = logits[b * EE + e];
        if (lv > v1) { v2 = v1; i2 = i1; v1 = lv; i1 = e; }
        else if (lv > v2) { v2 = lv; i2 = e; }
      }
      float e2 = expf(v2 - v1);
      float g1 = 1.f / (1.f + e2), g2 = e2 / (1.f + e2);
      for (int e = 0; e < EE; e++) ws[WS_GATES + b * EE + e] = 0.f;
      ws[WS_GATES + b * EE + i1] = g1;
      ws[WS_GATES + b * EE + i2] = g2;
      imp[i1] += g1; imp[i2] += g2;
      ld[i1] += 1.f; ld[i2] += 1.f;
    }
    float loss = 0.f;
    {
      float m = 0.f; for (int e = 0; e < EE; e++) m += imp[e]; m /= EE;
      float var = 0.f; for (int e = 0; e < EE; e++) { float d = imp[e] - m; var += d * d; }
      var /= (EE - 1);
      loss += var / (m * m + 1e-10f);
      m = 0.f; for (int e = 0; e < EE; e++) m += ld[e]; m /= EE;
      var = 0.f; for (int e = 0; e < EE; e++) { float d = ld[e] - m; var += d * d; }
      var /= (EE - 1);
      loss += var / (m * m + 1e-10f);
    }
    loss_out[0] = 0.01f * loss;
  }
}

// ---------------- Kernel 2.5: weight transform to MFMA-fragment order ----------------
// wt1 frag f = ((e*3+dx)*4+kc)*5+mt; elem = f*512 + lane*8 + j.
//   lane: row = lane&15 (co = mt*16+row), k = kc*32 + (lane>>4)*8 + j; k = dy*40+ci.
// wt2 frag f = ((e*3+dx)*7+kc)*3+mt; k = dy*72+ci, K=216.
__global__ __launch_bounds__(256) void wxform_kernel(const float* __restrict__ w1,
                                                     const float* __restrict__ w2,
                                                     unsigned short* __restrict__ wt1,
                                                     unsigned short* __restrict__ wt2) {
  int i = blockIdx.x * 256 + threadIdx.x;
  const int n1 = 360 * 512;
  if (i < n1) {
    int j = i & 7;
    int lane = (i >> 3) & 63;
    int f = i >> 9;
    int mt = f % 5;  f /= 5;
    int kc = f % 4;  f /= 4;
    int dx = f % 3;  int e = f / 3;
    int co = mt * 16 + (lane & 15);
    int k = kc * 32 + (lane >> 4) * 8 + j;
    int dy = k / 40, ci = k % 40;
    float v = 0.f;
    if (co < HID && k < 120 && ci < CCH)
      v = w1[(((size_t)(e * HID + co) * CCH + ci) * 3 + dy) * 3 + dx];
    wt1[i] = f2bf(v);
  }
  const int n2 = 378 * 512;
  if (i < n2) {
    int j = i & 7;
    int lane = (i >> 3) & 63;
    int f = i >> 9;
    int mt = f % 3;  f /= 3;
    int kc = f % 7;  f /= 7;
    int dx = f % 3;  int e = f / 3;
    int co = mt * 16 + (lane & 15);
    int k = kc * 32 + (lane >> 4) * 8 + j;
    int dy = k / 72, ci = k % 72;
    float v = 0.f;
    if (co < CCH && k < 216)
      v = w2[(((size_t)(e * CCH + co) * HID + ci) * 3 + dy) * 3 + dx];
    wt2[i] = f2bf(v);
  }
}

// ---------------- Kernel 3: fused MFMA conv1+GELU+conv2 ----------------
// Tile 32x2. xs [6][36][40] bf16; ts [4][34][72] bf16; weight slabs double-buffered,
// staged via async global_load_lds (linear, fragment-order), counted-vmcnt pipeline.
#define XCC 36
#define CIP 40
#define TCC 34
#define LDS_TS 17280
#define LDS_W  36864
#define WSLOT  21504
__global__ __launch_bounds__(256, 2) void conv_kernel(
    const float* __restrict__ x,
    const unsigned short* __restrict__ wt1,
    const unsigned short* __restrict__ wt2,
    const float* __restrict__ wsg,
    float* __restrict__ y) {
  __shared__ __align__(16) char lds[LDS_W + 2 * WSLOT];   // 79872 B
  char* xsB = lds;
  char* tsB = lds + LDS_TS;
  char* wB  = lds + LDS_W;

  const int tid = threadIdx.x;
  const int w = tid >> 6;
  const int lane = tid & 63;
  const int l15 = lane & 15;
  const int kl = lane >> 4;
  const int b = blockIdx.y;
  const int tx0 = (blockIdx.x & 7) * 32;
  const int ty0 = (blockIdx.x >> 3) * 2;
  const size_t xbase = (size_t)b * (CCH * HH * WW);

  // ---- active-expert list ----
  int eids[2] = {0, 0};
  float gvals[2] = {0.f, 0.f};
  int ne = 0;
  for (int e = 0; e < EE; e++) {
    float g = wsg[b * EE + e];
    if (g != 0.f && ne < 2) { eids[ne] = e; gvals[ne] = g; ne++; }
  }
  const int np = 6 * ne;

  // ---- async slab stage: phase p -> buffer (p&1). Returns #loads this wave issued.
  auto issue = [&](int p) -> int {
    int ei = p / 6, sub = p % 6;
    const char* src;
    int nch;
    if (sub < 3) { src = (const char*)wt1 + (size_t)(eids[ei] * 3 + sub) * 20480; nch = 20; }
    else         { src = (const char*)wt2 + (size_t)(eids[ei] * 3 + (sub - 3)) * 21504; nch = 21; }
    char* dst = wB + (p & 1) * WSLOT;
    int cnt = 0;
    for (int c = w; c < nch; c += 4, cnt++) {
      __builtin_amdgcn_global_load_lds(
          (const __attribute__((address_space(1))) void*)(src + c * 1024 + lane * 16),
          (__attribute__((address_space(3))) void*)(dst + c * 1024), 16, 0, 0);
    }
    return cnt;
  };

  if (np) issue(0);

  // ---- stage x tile (f32 -> bf16, ch-minor) ----
  for (int i = tid; i < 6 * XCC * CIP; i += 256) {
    int xc = i % XCC;
    int t2 = i / XCC;
    int xr = t2 % 6;
    int ci = t2 / 6;
    int gy = ty0 - 2 + xr, gx = tx0 - 2 + xc;
    float v = 0.f;
    if (ci < CCH && (unsigned)gy < (unsigned)HH && (unsigned)gx < (unsigned)WW)
      v = x[xbase + ((size_t)ci << 16) + (size_t)(gy * WW + gx)];
    *(unsigned short*)(xsB + 2 * ((xr * XCC + xc) * CIP + ci)) = f2bf(v);
  }

  // ---- per-lane K-chunk byte-offset tables (B side) ----
  int xkoff[4];
#pragma unroll
  for (int kc = 0; kc < 4; kc++) {
    int k0 = kc * 32 + kl * 8;
    int d = (k0 >= 80) ? 2 : (k0 >= 40 ? 1 : 0);
    xkoff[kc] = (k0 < 120) ? (d * XCC * CIP + (k0 - 40 * d)) * 2 : -1;
  }
  int tkoff[7];
#pragma unroll
  for (int kc = 0; kc < 7; kc++) {
    int k0 = kc * 32 + kl * 8;
    int d = (k0 >= 144) ? 2 : (k0 >= 72 ? 1 : 0);
    tkoff[kc] = (k0 < 216) ? (d * TCC * HID + (k0 - 72 * d)) * 2 : -1;
  }

  // ---- conv1 pixel coords (T grid 4x34=136px, 9 slots; wave w: slots w, w+4, w+8) ----
  const int nslot = (w == 0) ? 3 : 2;
  int pbase1[3], vimg[3], pst[3], trA[3], tcA[3];
#pragma unroll
  for (int i = 0; i < 3; i++) {
    int p = (w + 4 * i) * 16 + l15;
    int pr = p / 34;
    int tc = p - pr * 34;
    int prc = pr < 3 ? pr : 3;
    trA[i] = prc; tcA[i] = tc;
    pbase1[i] = (prc * XCC + tc) * CIP * 2;
    int gy = ty0 - 1 + pr, gx = tx0 - 1 + tc;
    pst[i] = (pr < 4) ? 1 : 0;
    vimg[i] = (pr < 4 && (unsigned)gy < (unsigned)HH && (unsigned)gx < (unsigned)WW) ? 1 : 0;
  }
  const int p2 = w * 16 + l15;
  const int or2 = p2 >> 5, oc2 = p2 & 31;
  const int pbase2 = (or2 * TCC + oc2) * HID * 2;

  f32x4 acc[3][5];
  f32x4 acc2[3];
  f32x4 yacc[3];
#pragma unroll
  for (int mt = 0; mt < 3; mt++) yacc[mt] = (f32x4){0.f, 0.f, 0.f, 0.f};

  // ---- pipelined phase loop: 6 phases per expert ----
  for (int p = 0; p < np; p++) {
    int nn = (p + 1 < np) ? issue(p + 1) : 0;
    if (nn == 6)      asm volatile("s_waitcnt vmcnt(6)" ::: "memory");
    else if (nn == 5) asm volatile("s_waitcnt vmcnt(5)" ::: "memory");
    else              asm volatile("s_waitcnt vmcnt(0)" ::: "memory");
    asm volatile("s_waitcnt lgkmcnt(0)" ::: "memory");
    __builtin_amdgcn_s_barrier();
    asm volatile("" ::: "memory");

    const int ei = p / 6, sub = p % 6;
    const char* wb = wB + (p & 1) * WSLOT;

    if (sub < 3) {
      if (sub == 0) {
#pragma unroll
        for (int i = 0; i < 3; i++)
#pragma unroll
          for (int mt = 0; mt < 5; mt++) acc[i][mt] = (f32x4){0.f, 0.f, 0.f, 0.f};
      }
      const int dxo = sub * (CIP * 2);
#pragma unroll
      for (int kc = 0; kc < 4; kc++) {
        bf16x8 bv[3];
#pragma unroll
        for (int i = 0; i < 3; i++) {
          if (i < nslot) {
            int ba = (xkoff[kc] >= 0) ? (pbase1[i] + xkoff[kc] + dxo) : 0;
            bv[i] = *(const bf16x8*)(xsB + ba);
          }
        }
#pragma unroll
        for (int mt = 0; mt < 5; mt++) {
          bf16x8 av = *(const bf16x8*)(wb + (kc * 5 + mt) * 1024 + lane * 16);
#pragma unroll
          for (int i = 0; i < 3; i++)
            if (i < nslot)
              acc[i][mt] = __builtin_amdgcn_mfma_f32_16x16x32_bf16(av, bv[i], acc[i][mt], 0, 0, 0);
        }
      }
      if (sub == 2) {
        // GELU + store T (bf16, ch-minor; exact 0 outside image)
#pragma unroll
        for (int i = 0; i < 3; i++) {
          if (i < nslot) {
#pragma unroll
            for (int mt = 0; mt < 5; mt++) {
              int co0 = mt * 16 + kl * 4;
              if (co0 < HID && pst[i]) {
                short4v pk;
                float v0 = vimg[i] ? gelu_fast(acc[i][mt].x) : 0.f;
                float v1 = vimg[i] ? gelu_fast(acc[i][mt].y) : 0.f;
                float v2 = vimg[i] ? gelu_fast(acc[i][mt].z) : 0.f;
                float v3 = vimg[i] ? gelu_fast(acc[i][mt].w) : 0.f;
                pk.x = (short)f2bf(v0); pk.y = (short)f2bf(v1);
                pk.z = (short)f2bf(v2); pk.w = (short)f2bf(v3);
                *(short4v*)(tsB + ((trA[i] * TCC + tcA[i]) * HID + co0) * 2) = pk;
              }
            }
          }
        }
      }
    } else {
      if (sub == 3) {
#pragma unroll
        for (int mt = 0; mt < 3; mt++) acc2[mt] = (f32x4){0.f, 0.f, 0.f, 0.f};
      }
      const int dxo = (sub - 3) * (HID * 2);
#pragma unroll
      for (int kc = 0; kc < 7; kc++) {
        int ba = (tkoff[kc] >= 0) ? (pbase2 + tkoff[kc] + dxo) : 0;
        bf16x8 bv = *(const bf16x8*)(tsB + ba);
#pragma unroll
        for (int mt = 0; mt < 3; mt++) {
          bf16x8 av = *(const bf16x8*)(wb + (kc * 3 + mt) * 1024 + lane * 16);
          acc2[mt] = __builtin_amdgcn_mfma_f32_16x16x32_bf16(av, bv, acc2[mt], 0, 0, 0);
        }
      }
      if (sub == 5) {
        const float gv = gvals[ei];
#pragma unroll
        for (int mt = 0; mt < 3; mt++) yacc[mt] += gv * acc2[mt];
      }
    }
  }

  // ---- store y (f32) ----
#pragma unroll
  for (int mt = 0; mt < 3; mt++) {
#pragma unroll
    for (int r = 0; r < 4; r++) {
      int co = mt * 16 + kl * 4 + r;
      if (co < CCH) {
        float v = (r == 0) ? yacc[mt].x : (r == 1) ? yacc[mt].y : (r == 2) ? yacc[mt].z : yacc[mt].w;
        y[xbase + ((size_t)co << 16) + (size_t)((ty0 + or2) * WW + tx0 + oc2)] = v;
      }
    }
  }
}

extern "C" void kernel_launch(void* const* d_in, const int* in_sizes, int n_in,
                              void* d_out, int out_size, void* d_ws, size_t ws_size,
                              hipStream_t stream) {
  const float* x      = (const float*)d_in[0];
  const float* time   = (const float*)d_in[1];
  const float* time_w = (const float*)d_in[2];
  const float* time_b = (const float*)d_in[3];
  const float* gw1    = (const float*)d_in[4];
  const float* gb1    = (const float*)d_in[5];
  const float* gw2    = (const float*)d_in[6];
  const float* gb2    = (const float*)d_in[7];
  const float* w1     = (const float*)d_in[8];
  const float* w2     = (const float*)d_in[9];
  float* out = (float*)d_out;
  float* ws  = (float*)d_ws;
  unsigned short* wt1 = (unsigned short*)((char*)d_ws + WT1_OFF);
  unsigned short* wt2 = (unsigned short*)((char*)d_ws + WT2_OFF);

  hipLaunchKernelGGL(pool_kernel, dim3(BB * CCH), dim3(256), 0, stream, x, ws);
  hipLaunchKernelGGL(gate_kernel, dim3(1), dim3(128), 0, stream,
                     time, time_w, time_b, gw1, gb1, gw2, gb2,
                     ws, out + (size_t)(out_size - 1));
  hipLaunchKernelGGL(wxform_kernel, dim3(756), dim3(256), 0, stream, w1, w2, wt1, wt2);
  hipLaunchKernelGGL(conv_kernel, dim3(1024, BB), dim3(256), 0, stream,
                     x, wt1, wt2, ws + WS_GATES, out);
}

// Round 6
// 414.336 us; speedup vs baseline: 2.0975x; 1.4373x over previous
//
#include <hip/hip_runtime.h>
#include <math.h>

#define BB 8
#define CCH 36
#define HH 256
#define WW 256
#define EE 6
#define TDIM 32
#define HID 72
// ws layout: floats [0,288) avg; [288,576) max; [576,624) gates.
// bytes: wt1 frags at 4096 (360 x 1024B); wt2 frags at 372736 (378 x 1024B).
#define WS_GATES (BB*CCH*2)
#define WT1_OFF 4096
#define WT2_OFF (4096 + 368640)

// conv geometry: 16w x 8t output tile, 4 waves
#define TW 16
#define TH 8
#define XR 12
#define XC 20
#define CIP 40
#define TR 10
#define TC 18

typedef __attribute__((ext_vector_type(8))) short bf16x8;
typedef __attribute__((ext_vector_type(4))) float f32x4;
typedef __attribute__((ext_vector_type(4))) short short4v;

static __device__ __forceinline__ unsigned short f2bf(float f) {
  union { float f; unsigned u; } v; v.f = f;
  unsigned r = v.u + 0x7FFF + ((v.u >> 16) & 1);
  return (unsigned short)(r >> 16);
}
// tanh-form GELU = x*e/(e+1), e=exp(2u), 2u = 1.59577x + 0.0713548x^3. |err| ~3e-4.
static __device__ __forceinline__ float gelu_fast(float x) {
  float u2 = x * (1.5957691216f + 0.0713548162f * x * x);
  u2 = fminf(fmaxf(u2, -30.f), 30.f);
  float e = __expf(u2);
  return x * e * __builtin_amdgcn_rcpf(e + 1.f);
}

// ---------------- Kernel 1: avg+max pool ----------------
__global__ __launch_bounds__(256) void pool_kernel(const float* __restrict__ x,
                                                   float* __restrict__ ws) {
  const int bc = blockIdx.x;
  const float* p = x + (size_t)bc * (HH * WW);
  float s = 0.f, m = -INFINITY;
  for (int i = threadIdx.x; i < (HH * WW) / 4; i += 256) {
    float4 v = ((const float4*)p)[i];
    s += v.x + v.y + v.z + v.w;
    m = fmaxf(m, fmaxf(fmaxf(v.x, v.y), fmaxf(v.z, v.w)));
  }
  for (int off = 32; off; off >>= 1) {
    s += __shfl_down(s, off);
    m = fmaxf(m, __shfl_down(m, off));
  }
  __shared__ float ss[4], sm[4];
  int wid = threadIdx.x >> 6, lane = threadIdx.x & 63;
  if (lane == 0) { ss[wid] = s; sm[wid] = m; }
  __syncthreads();
  if (threadIdx.x == 0) {
    float S = ss[0] + ss[1] + ss[2] + ss[3];
    float M = fmaxf(fmaxf(sm[0], sm[1]), fmaxf(sm[2], sm[3]));
    ws[bc] = S * (1.f / (HH * WW));
    ws[BB * CCH + bc] = M;
  }
}

// ---------------- Kernel 2: gating MLP + top-2 + loss ----------------
__global__ void gate_kernel(const float* __restrict__ time,
                            const float* __restrict__ time_w,
                            const float* __restrict__ time_b,
                            const float* __restrict__ w1, const float* __restrict__ b1,
                            const float* __restrict__ w2, const float* __restrict__ b2,
                            float* __restrict__ ws, float* __restrict__ loss_out) {
  __shared__ float v[BB * HID];
  __shared__ float h[BB * HID];
  __shared__ float logits[BB * EE];
  const int t = threadIdx.x;
  const float* avg = ws;
  const float* mx = ws + BB * CCH;
  for (int i = t; i < BB * HID; i += blockDim.x) {
    int b = i / HID, c = i % HID;
    float base = (c < CCH) ? avg[b * CCH + c] : mx[b * CCH + (c - CCH)];
    float acc = time_b[c];
    for (int k = 0; k < TDIM; k++) acc += time[b * TDIM + k] * time_w[k * HID + c];
    v[i] = base + acc;
  }
  __syncthreads();
  for (int i = t; i < BB * HID; i += blockDim.x) {
    int b = i / HID, c = i % HID;
    float acc = b1[c];
    for (int k = 0; k < HID; k++) acc += v[b * HID + k] * w1[k * HID + c];
    h[i] = acc > 0.f ? acc : 0.01f * acc;
  }
  __syncthreads();
  for (int i = t; i < BB * EE; i += blockDim.x) {
    int b = i / EE, e = i % EE;
    float acc = b2[e];
    for (int k = 0; k < HID; k++) acc += h[b * HID + k] * w2[k * EE + e];
    logits[i] = acc;
  }
  __syncthreads();
  if (t == 0) {
    float imp[EE], ld[EE];
    for (int e = 0; e < EE; e++) { imp[e] = 0.f; ld[e] = 0.f; }
    for (int b = 0; b < BB; b++) {
      int i1 = -1, i2 = -1;
      float v1 = -1e30f, v2 = -1e30f;
      for (int e = 0; e < EE; e++) {
        float lv = logits[b * EE + e];
        if (lv > v1) { v2 = v1; i2 = i1; v1 = lv; i1 = e; }
        else if (lv > v2) { v2 = lv; i2 = e; }
      }
      float e2 = expf(v2 - v1);
      float g1 = 1.f / (1.f + e2), g2 = e2 / (1.f + e2);
      for (int e = 0; e < EE; e++) ws[WS_GATES + b * EE + e] = 0.f;
      ws[WS_GATES + b * EE + i1] = g1;
      ws[WS_GATES + b * EE + i2] = g2;
      imp[i1] += g1; imp[i2] += g2;
      ld[i1] += 1.f; ld[i2] += 1.f;
    }
    float loss = 0.f;
    {
      float m = 0.f; for (int e = 0; e < EE; e++) m += imp[e]; m /= EE;
      float var = 0.f; for (int e = 0; e < EE; e++) { float d = imp[e] - m; var += d * d; }
      var /= (EE - 1);
      loss += var / (m * m + 1e-10f);
      m = 0.f; for (int e = 0; e < EE; e++) m += ld[e]; m /= EE;
      var = 0.f; for (int e = 0; e < EE; e++) { float d = ld[e] - m; var += d * d; }
      var /= (EE - 1);
      loss += var / (m * m + 1e-10f);
    }
    loss_out[0] = 0.01f * loss;
  }
}

// ---------------- Kernel 2.5: weight transform to MFMA-fragment order ----------------
// wt1 frag f = ((e*3+dx)*4+kc)*5+mt; elem = f*512 + lane*8 + j.
//   co = mt*16 + (lane&15); k = kc*32 + (lane>>4)*8 + j; k = dy*40+ci, K=120.
// wt2 frag f = ((e*3+dx)*7+kc)*3+mt; k = dy*72+ci, K=216.
__global__ __launch_bounds__(256) void wxform_kernel(const float* __restrict__ w1,
                                                     const float* __restrict__ w2,
                                                     unsigned short* __restrict__ wt1,
                                                     unsigned short* __restrict__ wt2) {
  int i = blockIdx.x * 256 + threadIdx.x;
  const int n1 = 360 * 512;
  if (i < n1) {
    int j = i & 7;
    int lane = (i >> 3) & 63;
    int f = i >> 9;
    int mt = f % 5;  f /= 5;
    int kc = f % 4;  f /= 4;
    int dx = f % 3;  int e = f / 3;
    int co = mt * 16 + (lane & 15);
    int k = kc * 32 + (lane >> 4) * 8 + j;
    int dy = k / 40, ci = k % 40;
    float v = 0.f;
    if (co < HID && k < 120 && ci < CCH)
      v = w1[(((size_t)(e * HID + co) * CCH + ci) * 3 + dy) * 3 + dx];
    wt1[i] = f2bf(v);
  }
  const int n2 = 378 * 512;
  if (i < n2) {
    int j = i & 7;
    int lane = (i >> 3) & 63;
    int f = i >> 9;
    int mt = f % 3;  f /= 3;
    int kc = f % 7;  f /= 7;
    int dx = f % 3;  int e = f / 3;
    int co = mt * 16 + (lane & 15);
    int k = kc * 32 + (lane >> 4) * 8 + j;
    int dy = k / 72, ci = k % 72;
    float v = 0.f;
    if (co < CCH && k < 216)
      v = w2[(((size_t)(e * CCH + co) * HID + ci) * 3 + dy) * 3 + dx];
    wt2[i] = f2bf(v);
  }
}

// ---------------- Kernel 3: fused MFMA conv1+GELU+conv2 ----------------
// Tile 16x8, 4 waves. LDS: xs [12][20][40] bf16 + ts [10][18][72] bf16 = 45120 B
// -> 3 blocks/CU. Weight A-fragments stream from global (L2) with register
// double-buffer prefetch; weights never touch LDS.
__global__ __launch_bounds__(256, 3) void conv_kernel(
    const float* __restrict__ x,
    const unsigned short* __restrict__ wt1,
    const unsigned short* __restrict__ wt2,
    const float* __restrict__ wsg,
    float* __restrict__ y) {
  __shared__ __align__(16) char lds[45120];
  char* xsB = lds;                 // 19200 B
  char* tsB = lds + 19200;         // 25920 B

  const int tid = threadIdx.x;
  const int w = tid >> 6;
  const int lane = tid & 63;
  const int l15 = lane & 15;
  const int kl = lane >> 4;
  const int b = blockIdx.y;
  const int tx0 = (blockIdx.x & 15) * TW;
  const int ty0 = (blockIdx.x >> 4) * TH;
  const size_t xbase = (size_t)b * (CCH * HH * WW);

  // active experts
  int eids[2] = {0, 0};
  float gvals[2] = {0.f, 0.f};
  int ne = 0;
  for (int e = 0; e < EE; e++) {
    float g = wsg[b * EE + e];
    if (g != 0.f && ne < 2) { eids[ne] = e; gvals[ne] = g; ne++; }
  }

  // ---- stage x tile [12][20][40] bf16 (ci-minor; zeros outside image / ci>=36) ----
  for (int i = tid; i < XR * XC * CIP; i += 256) {
    int xc = i % XC;
    int t2 = i / XC;
    int xr = t2 % XR;
    int ci = t2 / XR;
    int gy = ty0 - 2 + xr, gx = tx0 - 2 + xc;
    float v = 0.f;
    if (ci < CCH && (unsigned)gy < (unsigned)HH && (unsigned)gx < (unsigned)WW)
      v = x[xbase + ((size_t)ci << 16) + (size_t)(gy * WW + gx)];
    *(unsigned short*)(xsB + 2 * ((xr * XC + xc) * CIP + ci)) = f2bf(v);
  }

  // ---- per-lane K-chunk byte offsets ----
  int xkoff[4];
#pragma unroll
  for (int kc = 0; kc < 4; kc++) {
    int k0 = kc * 32 + kl * 8;
    int d = (k0 >= 80) ? 2 : (k0 >= 40 ? 1 : 0);
    xkoff[kc] = (k0 < 120) ? (d * (XC * CIP) + (k0 - 40 * d)) * 2 : -1;
  }
  int tkoff[7];
#pragma unroll
  for (int kc = 0; kc < 7; kc++) {
    int k0 = kc * 32 + kl * 8;
    int d = (k0 >= 144) ? 2 : (k0 >= 72 ? 1 : 0);
    tkoff[kc] = (k0 < 216) ? (d * (TC * HID) + (k0 - 72 * d)) * 2 : -1;
  }

  // ---- conv1 pixel coords: T grid 10x18=180 px, 12 slots; wave w owns w,w+4,w+8 ----
  int pbase1[3], tsoff[3], vimg[3], pst[3];
#pragma unroll
  for (int i = 0; i < 3; i++) {
    int p = (w + 4 * i) * 16 + l15;
    int tr = p / TC, tc = p - tr * TC;
    pst[i] = (p < TR * TC) ? 1 : 0;
    int trc = tr < (TR - 1) ? tr : (TR - 1);
    pbase1[i] = (trc * XC + tc) * (CIP * 2);
    tsoff[i] = ((trc * TC + tc) * HID) * 2;
    int gy = ty0 - 1 + tr, gx = tx0 - 1 + tc;
    vimg[i] = (pst[i] && (unsigned)gy < (unsigned)HH && (unsigned)gx < (unsigned)WW) ? 1 : 0;
  }
  // conv2: 8 rows = 8 slots; wave w owns rows w, w+4. col = l15.
  int pbase2[2];
#pragma unroll
  for (int i = 0; i < 2; i++) pbase2[i] = (((w + 4 * i) * TC) + l15) * (HID * 2);

  const unsigned short* w1lane = wt1 + lane * 8;
  const unsigned short* w2lane = wt2 + lane * 8;

  f32x4 yacc[2][3];
#pragma unroll
  for (int i = 0; i < 2; i++)
#pragma unroll
    for (int mt = 0; mt < 3; mt++) yacc[i][mt] = (f32x4){0.f, 0.f, 0.f, 0.f};

  __syncthreads();

#pragma unroll
  for (int ei = 0; ei < 2; ei++) {
    if (ei >= ne) break;
    const float gv = gvals[ei];
    const unsigned short* w1p = w1lane + eids[ei] * 30720;   // 3*80*128
    const unsigned short* w2p = w2lane + eids[ei] * 32256;   // 3*48*224

    // ================= conv1: 12 steps (dx*4+kc), A double-buffered =================
    f32x4 acc[3][5];
#pragma unroll
    for (int i = 0; i < 3; i++)
#pragma unroll
      for (int mt = 0; mt < 5; mt++) acc[i][mt] = (f32x4){0.f, 0.f, 0.f, 0.f};

    bf16x8 aA[5], aB[5];
#pragma unroll
    for (int mt = 0; mt < 5; mt++) aA[mt] = *(const bf16x8*)(w1p + mt * 512);

#pragma unroll
    for (int jj = 0; jj < 12; jj++) {
      if (jj < 11) {
#pragma unroll
        for (int mt = 0; mt < 5; mt++)
          ((jj & 1) ? aA : aB)[mt] = *(const bf16x8*)(w1p + ((jj + 1) * 5 + mt) * 512);
      }
      const int kc = jj & 3;
      const int dxo = (jj >> 2) * (CIP * 2);
      bf16x8 bv[3];
#pragma unroll
      for (int i = 0; i < 3; i++) {
        int ba = (xkoff[kc] >= 0) ? (pbase1[i] + xkoff[kc] + dxo) : 0;
        bv[i] = *(const bf16x8*)(xsB + ba);
      }
#pragma unroll
      for (int mt = 0; mt < 5; mt++) {
        bf16x8 av = ((jj & 1) ? aB : aA)[mt];
#pragma unroll
        for (int i = 0; i < 3; i++)
          acc[i][mt] = __builtin_amdgcn_mfma_f32_16x16x32_bf16(av, bv[i], acc[i][mt], 0, 0, 0);
      }
    }

    // preload conv2 first frag-group (latency hides under GELU/store)
    bf16x8 cA[3], cB[3];
#pragma unroll
    for (int mt = 0; mt < 3; mt++) cA[mt] = *(const bf16x8*)(w2p + mt * 512);

    // ---- GELU + store T (exact 0 outside image) ----
#pragma unroll
    for (int i = 0; i < 3; i++) {
      if (pst[i]) {
#pragma unroll
        for (int mt = 0; mt < 5; mt++) {
          int co0 = mt * 16 + kl * 4;
          if (co0 < HID) {
            short4v pk;
            float v0 = vimg[i] ? gelu_fast(acc[i][mt].x) : 0.f;
            float v1 = vimg[i] ? gelu_fast(acc[i][mt].y) : 0.f;
            float v2 = vimg[i] ? gelu_fast(acc[i][mt].z) : 0.f;
            float v3 = vimg[i] ? gelu_fast(acc[i][mt].w) : 0.f;
            pk.x = (short)f2bf(v0); pk.y = (short)f2bf(v1);
            pk.z = (short)f2bf(v2); pk.w = (short)f2bf(v3);
            *(short4v*)(tsB + tsoff[i] + co0 * 2) = pk;
          }
        }
      }
    }
    __syncthreads();

    // ================= conv2: 21 steps (dx*7+kc), A double-buffered =================
    f32x4 acc2[2][3];
#pragma unroll
    for (int i = 0; i < 2; i++)
#pragma unroll
      for (int mt = 0; mt < 3; mt++) acc2[i][mt] = (f32x4){0.f, 0.f, 0.f, 0.f};

#pragma unroll
    for (int jj = 0; jj < 21; jj++) {
      if (jj < 20) {
#pragma unroll
        for (int mt = 0; mt < 3; mt++)
          ((jj & 1) ? cA : cB)[mt] = *(const bf16x8*)(w2p + ((jj + 1) * 3 + mt) * 512);
      }
      const int kc = jj % 7;
      const int dxo = (jj / 7) * (HID * 2);
      bf16x8 bv[2];
#pragma unroll
      for (int i = 0; i < 2; i++) {
        int ba = (tkoff[kc] >= 0) ? (pbase2[i] + tkoff[kc] + dxo) : 0;
        bv[i] = *(const bf16x8*)(tsB + ba);
      }
#pragma unroll
      for (int mt = 0; mt < 3; mt++) {
        bf16x8 av = ((jj & 1) ? cB : cA)[mt];
#pragma unroll
        for (int i = 0; i < 2; i++)
          acc2[i][mt] = __builtin_amdgcn_mfma_f32_16x16x32_bf16(av, bv[i], acc2[i][mt], 0, 0, 0);
      }
    }
#pragma unroll
    for (int i = 0; i < 2; i++)
#pragma unroll
      for (int mt = 0; mt < 3; mt++) yacc[i][mt] += gv * acc2[i][mt];
    __syncthreads();   // ts free for next expert
  }

  // ---- store y (f32) ----
#pragma unroll
  for (int i = 0; i < 2; i++) {
    int row = w + 4 * i;
#pragma unroll
    for (int mt = 0; mt < 3; mt++) {
#pragma unroll
      for (int r = 0; r < 4; r++) {
        int co = mt * 16 + kl * 4 + r;
        if (co < CCH) {
          float v = (r == 0) ? yacc[i][mt].x : (r == 1) ? yacc[i][mt].y
                  : (r == 2) ? yacc[i][mt].z : yacc[i][mt].w;
          y[xbase + ((size_t)co << 16) + (size_t)((ty0 + row) * WW + tx0 + l15)] = v;
        }
      }
    }
  }
}

extern "C" void kernel_launch(void* const* d_in, const int* in_sizes, int n_in,
                              void* d_out, int out_size, void* d_ws, size_t ws_size,
                              hipStream_t stream) {
  const float* x      = (const float*)d_in[0];
  const float* time   = (const float*)d_in[1];
  const float* time_w = (const float*)d_in[2];
  const float* time_b = (const float*)d_in[3];
  const float* gw1    = (const float*)d_in[4];
  const float* gb1    = (const float*)d_in[5];
  const float* gw2    = (const float*)d_in[6];
  const float* gb2    = (const float*)d_in[7];
  const float* w1     = (const float*)d_in[8];
  const float* w2     = (const float*)d_in[9];
  float* out = (float*)d_out;
  float* ws  = (float*)d_ws;
  unsigned short* wt1 = (unsigned short*)((char*)d_ws + WT1_OFF);
  unsigned short* wt2 = (unsigned short*)((char*)d_ws + WT2_OFF);

  hipLaunchKernelGGL(pool_kernel, dim3(BB * CCH), dim3(256), 0, stream, x, ws);
  hipLaunchKernelGGL(gate_kernel, dim3(1), dim3(128), 0, stream,
                     time, time_w, time_b, gw1, gb1, gw2, gb2,
                     ws, out + (size_t)(out_size - 1));
  hipLaunchKernelGGL(wxform_kernel, dim3(756), dim3(256), 0, stream, w1, w2, wt1, wt2);
  hipLaunchKernelGGL(conv_kernel, dim3(512, BB), dim3(256), 0, stream,
                     x, wt1, wt2, ws + WS_GATES, out);
}

// Round 7
// 251.631 us; speedup vs baseline: 3.4538x; 1.6466x over previous
//
#include <hip/hip_runtime.h>
#include <math.h>

#define BB 8
#define CCH 36
#define HH 256
#define WW 256
#define EE 6
#define TDIM 32
#define HID 72
// ws layout: floats [0,288) avg; [288,576) max; [576,624) gates.
// bytes: wt1 frags at 4096 (360 x 1024B); wt2 frags at 372736 (378 x 1024B).
#define WS_GATES (BB*CCH*2)
#define WT1_OFF 4096
#define WT2_OFF (4096 + 368640)

// conv geometry: 16w x 8t output tile, 4 waves
#define TW 16
#define TH 8
#define XR 12
#define XC 20
#define CIP 40
#define TR 10
#define TC 18

typedef __attribute__((ext_vector_type(8))) short bf16x8;
typedef __attribute__((ext_vector_type(4))) float f32x4;
typedef __attribute__((ext_vector_type(4))) short short4v;

static __device__ __forceinline__ unsigned short f2bf(float f) {
  union { float f; unsigned u; } v; v.f = f;
  unsigned r = v.u + 0x7FFF + ((v.u >> 16) & 1);
  return (unsigned short)(r >> 16);
}
// tanh-form GELU = x*e/(e+1), e=exp(2u), 2u = 1.59577x + 0.0713548x^3. |err| ~3e-4.
static __device__ __forceinline__ float gelu_fast(float x) {
  float u2 = x * (1.5957691216f + 0.0713548162f * x * x);
  u2 = fminf(fmaxf(u2, -30.f), 30.f);
  float e = __expf(u2);
  return x * e * __builtin_amdgcn_rcpf(e + 1.f);
}

// ---------------- Kernel 1: avg+max pool ----------------
__global__ __launch_bounds__(256) void pool_kernel(const float* __restrict__ x,
                                                   float* __restrict__ ws) {
  const int bc = blockIdx.x;
  const float* p = x + (size_t)bc * (HH * WW);
  float s = 0.f, m = -INFINITY;
  for (int i = threadIdx.x; i < (HH * WW) / 4; i += 256) {
    float4 v = ((const float4*)p)[i];
    s += v.x + v.y + v.z + v.w;
    m = fmaxf(m, fmaxf(fmaxf(v.x, v.y), fmaxf(v.z, v.w)));
  }
  for (int off = 32; off; off >>= 1) {
    s += __shfl_down(s, off);
    m = fmaxf(m, __shfl_down(m, off));
  }
  __shared__ float ss[4], sm[4];
  int wid = threadIdx.x >> 6, lane = threadIdx.x & 63;
  if (lane == 0) { ss[wid] = s; sm[wid] = m; }
  __syncthreads();
  if (threadIdx.x == 0) {
    float S = ss[0] + ss[1] + ss[2] + ss[3];
    float M = fmaxf(fmaxf(sm[0], sm[1]), fmaxf(sm[2], sm[3]));
    ws[bc] = S * (1.f / (HH * WW));
    ws[BB * CCH + bc] = M;
  }
}

// ---------------- Kernel 2: gating MLP + top-2 + loss ----------------
__global__ void gate_kernel(const float* __restrict__ time,
                            const float* __restrict__ time_w,
                            const float* __restrict__ time_b,
                            const float* __restrict__ w1, const float* __restrict__ b1,
                            const float* __restrict__ w2, const float* __restrict__ b2,
                            float* __restrict__ ws, float* __restrict__ loss_out) {
  __shared__ float v[BB * HID];
  __shared__ float h[BB * HID];
  __shared__ float logits[BB * EE];
  const int t = threadIdx.x;
  const float* avg = ws;
  const float* mx = ws + BB * CCH;
  for (int i = t; i < BB * HID; i += blockDim.x) {
    int b = i / HID, c = i % HID;
    float base = (c < CCH) ? avg[b * CCH + c] : mx[b * CCH + (c - CCH)];
    float acc = time_b[c];
    for (int k = 0; k < TDIM; k++) acc += time[b * TDIM + k] * time_w[k * HID + c];
    v[i] = base + acc;
  }
  __syncthreads();
  for (int i = t; i < BB * HID; i += blockDim.x) {
    int b = i / HID, c = i % HID;
    float acc = b1[c];
    for (int k = 0; k < HID; k++) acc += v[b * HID + k] * w1[k * HID + c];
    h[i] = acc > 0.f ? acc : 0.01f * acc;
  }
  __syncthreads();
  for (int i = t; i < BB * EE; i += blockDim.x) {
    int b = i / EE, e = i % EE;
    float acc = b2[e];
    for (int k = 0; k < HID; k++) acc += h[b * HID + k] * w2[k * EE + e];
    logits[i] = acc;
  }
  __syncthreads();
  if (t == 0) {
    float imp[EE], ld[EE];
    for (int e = 0; e < EE; e++) { imp[e] = 0.f; ld[e] = 0.f; }
    for (int b = 0; b < BB; b++) {
      int i1 = -1, i2 = -1;
      float v1 = -1e30f, v2 = -1e30f;
      for (int e = 0; e < EE; e++) {
        float lv = logits[b * EE + e];
        if (lv > v1) { v2 = v1; i2 = i1; v1 = lv; i1 = e; }
        else if (lv > v2) { v2 = lv; i2 = e; }
      }
      float e2 = expf(v2 - v1);
      float g1 = 1.f / (1.f + e2), g2 = e2 / (1.f + e2);
      for (int e = 0; e < EE; e++) ws[WS_GATES + b * EE + e] = 0.f;
      ws[WS_GATES + b * EE + i1] = g1;
      ws[WS_GATES + b * EE + i2] = g2;
      imp[i1] += g1; imp[i2] += g2;
      ld[i1] += 1.f; ld[i2] += 1.f;
    }
    float loss = 0.f;
    {
      float m = 0.f; for (int e = 0; e < EE; e++) m += imp[e]; m /= EE;
      float var = 0.f; for (int e = 0; e < EE; e++) { float d = imp[e] - m; var += d * d; }
      var /= (EE - 1);
      loss += var / (m * m + 1e-10f);
      m = 0.f; for (int e = 0; e < EE; e++) m += ld[e]; m /= EE;
      var = 0.f; for (int e = 0; e < EE; e++) { float d = ld[e] - m; var += d * d; }
      var /= (EE - 1);
      loss += var / (m * m + 1e-10f);
    }
    loss_out[0] = 0.01f * loss;
  }
}

// ---------------- Kernel 2.5: weight transform to MFMA-fragment order ----------------
// wt1 frag f = ((e*3+dx)*4+kc)*5+mt; elem = f*512 + lane*8 + j.
//   co = mt*16 + (lane&15); k = kc*32 + (lane>>4)*8 + j; k = dy*40+ci, K=120.
// wt2 frag f = ((e*3+dx)*7+kc)*3+mt; k = dy*72+ci, K=216.
__global__ __launch_bounds__(256) void wxform_kernel(const float* __restrict__ w1,
                                                     const float* __restrict__ w2,
                                                     unsigned short* __restrict__ wt1,
                                                     unsigned short* __restrict__ wt2) {
  int i = blockIdx.x * 256 + threadIdx.x;
  const int n1 = 360 * 512;
  if (i < n1) {
    int j = i & 7;
    int lane = (i >> 3) & 63;
    int f = i >> 9;
    int mt = f % 5;  f /= 5;
    int kc = f % 4;  f /= 4;
    int dx = f % 3;  int e = f / 3;
    int co = mt * 16 + (lane & 15);
    int k = kc * 32 + (lane >> 4) * 8 + j;
    int dy = k / 40, ci = k % 40;
    float v = 0.f;
    if (co < HID && k < 120 && ci < CCH)
      v = w1[(((size_t)(e * HID + co) * CCH + ci) * 3 + dy) * 3 + dx];
    wt1[i] = f2bf(v);
  }
  const int n2 = 378 * 512;
  if (i < n2) {
    int j = i & 7;
    int lane = (i >> 3) & 63;
    int f = i >> 9;
    int mt = f % 3;  f /= 3;
    int kc = f % 7;  f /= 7;
    int dx = f % 3;  int e = f / 3;
    int co = mt * 16 + (lane & 15);
    int k = kc * 32 + (lane >> 4) * 8 + j;
    int dy = k / 72, ci = k % 72;
    float v = 0.f;
    if (co < CCH && k < 216)
      v = w2[(((size_t)(e * CCH + co) * HID + ci) * 3 + dy) * 3 + dx];
    wt2[i] = f2bf(v);
  }
}

// ---------------- Kernel 3: fused MFMA conv1+GELU+conv2 ----------------
// Tile 16x8, 4 waves. LDS: xs [12][20][40] bf16 + ts [10][18][72] bf16 = 45120 B
// -> 3 blocks/CU. Weight A-fragments stream from global (L1/L2, fragment-order)
// with register double-buffer prefetch. XCD-chunked tile swizzle for halo L2 reuse.
__global__ __launch_bounds__(256, 3) void conv_kernel(
    const float* __restrict__ x,
    const unsigned short* __restrict__ wt1,
    const unsigned short* __restrict__ wt2,
    const float* __restrict__ wsg,
    float* __restrict__ y) {
  __shared__ __align__(16) char lds[45120];
  char* xsB = lds;                 // 19200 B
  char* tsB = lds + 19200;         // 25920 B

  const int tid = threadIdx.x;
  const int w = tid >> 6;
  const int lane = tid & 63;
  const int l15 = lane & 15;
  const int kl = lane >> 4;
  const int b = blockIdx.y;
  // XCD-chunked swizzle: each XCD (8 total) gets a contiguous band of 64 tiles
  // (4 tile-rows) per image -> vertical halo reuse hits that XCD's L2.
  const int tileId = (blockIdx.x & 7) * 64 + (blockIdx.x >> 3);
  const int tx0 = (tileId & 15) * TW;
  const int ty0 = (tileId >> 4) * TH;
  const size_t xbase = (size_t)b * (CCH * HH * WW);

  // active experts
  int eids[2] = {0, 0};
  float gvals[2] = {0.f, 0.f};
  int ne = 0;
  for (int e = 0; e < EE; e++) {
    float g = wsg[b * EE + e];
    if (g != 0.f && ne < 2) { eids[ne] = e; gvals[ne] = g; ne++; }
  }

  // ---- stage x tile [12][20][40] bf16 (ci-minor): one thread owns one (xr,xc) ----
  if (tid < XR * XC) {
    const int xr = tid / XC, xc = tid - (tid / XC) * XC;
    const int gy = ty0 - 2 + xr, gx = tx0 - 2 + xc;
    const bool valid = ((unsigned)gy < (unsigned)HH) && ((unsigned)gx < (unsigned)WW);
    const float* xp = x + xbase + (size_t)(gy * WW + gx);
    char* dstb = xsB + 2 * ((xr * XC + xc) * CIP);
#pragma unroll
    for (int c4 = 0; c4 < 9; c4++) {
      short4v pk;
#pragma unroll
      for (int q = 0; q < 4; q++) {
        int ci = c4 * 4 + q;
        float v = valid ? xp[(size_t)ci << 16] : 0.f;
        ((short*)&pk)[q] = (short)f2bf(v);
      }
      *(short4v*)(dstb + c4 * 8) = pk;
    }
    *(short4v*)(dstb + 72) = (short4v){0, 0, 0, 0};   // ci 36..39 pad
  }

  // ---- per-lane K-chunk byte offsets ----
  int xkoff[4];
#pragma unroll
  for (int kc = 0; kc < 4; kc++) {
    int k0 = kc * 32 + kl * 8;
    int d = (k0 >= 80) ? 2 : (k0 >= 40 ? 1 : 0);
    xkoff[kc] = (k0 < 120) ? (d * (XC * CIP) + (k0 - 40 * d)) * 2 : -1;
  }
  int tkoff[7];
#pragma unroll
  for (int kc = 0; kc < 7; kc++) {
    int k0 = kc * 32 + kl * 8;
    int d = (k0 >= 144) ? 2 : (k0 >= 72 ? 1 : 0);
    tkoff[kc] = (k0 < 216) ? (d * (TC * HID) + (k0 - 72 * d)) * 2 : -1;
  }

  // ---- conv1 pixel coords: T grid 10x18=180 px, 12 slots; wave w owns w,w+4,w+8 ----
  int pbase1[3], tsoff[3], vimg[3], pst[3];
#pragma unroll
  for (int i = 0; i < 3; i++) {
    int p = (w + 4 * i) * 16 + l15;
    int tr = p / TC, tc = p - tr * TC;
    pst[i] = (p < TR * TC) ? 1 : 0;
    int trc = tr < (TR - 1) ? tr : (TR - 1);
    pbase1[i] = (trc * XC + tc) * (CIP * 2);
    tsoff[i] = ((trc * TC + tc) * HID) * 2;
    int gy = ty0 - 1 + tr, gx = tx0 - 1 + tc;
    vimg[i] = (pst[i] && (unsigned)gy < (unsigned)HH && (unsigned)gx < (unsigned)WW) ? 1 : 0;
  }
  // conv2: 8 rows = 8 slots; wave w owns rows w, w+4. col = l15.
  int pbase2[2];
#pragma unroll
  for (int i = 0; i < 2; i++) pbase2[i] = (((w + 4 * i) * TC) + l15) * (HID * 2);

  const unsigned short* w1lane = wt1 + lane * 8;
  const unsigned short* w2lane = wt2 + lane * 8;

  f32x4 yacc[2][3];
#pragma unroll
  for (int i = 0; i < 2; i++)
#pragma unroll
    for (int mt = 0; mt < 3; mt++) yacc[i][mt] = (f32x4){0.f, 0.f, 0.f, 0.f};

  __syncthreads();

#pragma unroll
  for (int ei = 0; ei < 2; ei++) {
    if (ei >= ne) break;
    const float gv = gvals[ei];
    const unsigned short* w1p = w1lane + eids[ei] * 30720;   // 3*80*128
    const unsigned short* w2p = w2lane + eids[ei] * 32256;   // 3*48*224

    // ================= conv1: 12 steps (dx*4+kc), A double-buffered =================
    f32x4 acc[3][5];
#pragma unroll
    for (int i = 0; i < 3; i++)
#pragma unroll
      for (int mt = 0; mt < 5; mt++) acc[i][mt] = (f32x4){0.f, 0.f, 0.f, 0.f};

    bf16x8 aA[5], aB[5];
#pragma unroll
    for (int mt = 0; mt < 5; mt++) aA[mt] = *(const bf16x8*)(w1p + mt * 512);

#pragma unroll
    for (int jj = 0; jj < 12; jj++) {
      if (jj < 11) {
#pragma unroll
        for (int mt = 0; mt < 5; mt++)
          ((jj & 1) ? aA : aB)[mt] = *(const bf16x8*)(w1p + ((jj + 1) * 5 + mt) * 512);
      }
      const int kc = jj & 3;
      const int dxo = (jj >> 2) * (CIP * 2);
      bf16x8 bv[3];
#pragma unroll
      for (int i = 0; i < 3; i++) {
        int ba = (xkoff[kc] >= 0) ? (pbase1[i] + xkoff[kc] + dxo) : 0;
        bv[i] = *(const bf16x8*)(xsB + ba);
      }
      __builtin_amdgcn_s_setprio(1);
#pragma unroll
      for (int mt = 0; mt < 5; mt++) {
        bf16x8 av = ((jj & 1) ? aB : aA)[mt];
#pragma unroll
        for (int i = 0; i < 3; i++)
          acc[i][mt] = __builtin_amdgcn_mfma_f32_16x16x32_bf16(av, bv[i], acc[i][mt], 0, 0, 0);
      }
      __builtin_amdgcn_s_setprio(0);
    }

    // preload conv2 first frag-group (latency hides under GELU/store)
    bf16x8 cA[3], cB[3];
#pragma unroll
    for (int mt = 0; mt < 3; mt++) cA[mt] = *(const bf16x8*)(w2p + mt * 512);

    // ---- GELU + store T (exact 0 outside image) ----
#pragma unroll
    for (int i = 0; i < 3; i++) {
      if (pst[i]) {
#pragma unroll
        for (int mt = 0; mt < 5; mt++) {
          int co0 = mt * 16 + kl * 4;
          if (co0 < HID) {
            short4v pk;
            float v0 = vimg[i] ? gelu_fast(acc[i][mt].x) : 0.f;
            float v1 = vimg[i] ? gelu_fast(acc[i][mt].y) : 0.f;
            float v2 = vimg[i] ? gelu_fast(acc[i][mt].z) : 0.f;
            float v3 = vimg[i] ? gelu_fast(acc[i][mt].w) : 0.f;
            pk.x = (short)f2bf(v0); pk.y = (short)f2bf(v1);
            pk.z = (short)f2bf(v2); pk.w = (short)f2bf(v3);
            *(short4v*)(tsB + tsoff[i] + co0 * 2) = pk;
          }
        }
      }
    }
    __syncthreads();

    // ================= conv2: 21 steps (dx*7+kc), A double-buffered =================
    f32x4 acc2[2][3];
#pragma unroll
    for (int i = 0; i < 2; i++)
#pragma unroll
      for (int mt = 0; mt < 3; mt++) acc2[i][mt] = (f32x4){0.f, 0.f, 0.f, 0.f};

#pragma unroll
    for (int jj = 0; jj < 21; jj++) {
      if (jj < 20) {
#pragma unroll
        for (int mt = 0; mt < 3; mt++)
          ((jj & 1) ? cA : cB)[mt] = *(const bf16x8*)(w2p + ((jj + 1) * 3 + mt) * 512);
      }
      const int kc = jj % 7;
      const int dxo = (jj / 7) * (HID * 2);
      bf16x8 bv[2];
#pragma unroll
      for (int i = 0; i < 2; i++) {
        int ba = (tkoff[kc] >= 0) ? (pbase2[i] + tkoff[kc] + dxo) : 0;
        bv[i] = *(const bf16x8*)(tsB + ba);
      }
      __builtin_amdgcn_s_setprio(1);
#pragma unroll
      for (int mt = 0; mt < 3; mt++) {
        bf16x8 av = ((jj & 1) ? cB : cA)[mt];
#pragma unroll
        for (int i = 0; i < 2; i++)
          acc2[i][mt] = __builtin_amdgcn_mfma_f32_16x16x32_bf16(av, bv[i], acc2[i][mt], 0, 0, 0);
      }
      __builtin_amdgcn_s_setprio(0);
    }
#pragma unroll
    for (int i = 0; i < 2; i++)
#pragma unroll
      for (int mt = 0; mt < 3; mt++) yacc[i][mt] += gv * acc2[i][mt];
    __syncthreads();   // ts free for next expert
  }

  // ---- store y (f32) ----
#pragma unroll
  for (int i = 0; i < 2; i++) {
    int row = w + 4 * i;
#pragma unroll
    for (int mt = 0; mt < 3; mt++) {
#pragma unroll
      for (int r = 0; r < 4; r++) {
        int co = mt * 16 + kl * 4 + r;
        if (co < CCH) {
          float v = (r == 0) ? yacc[i][mt].x : (r == 1) ? yacc[i][mt].y
                  : (r == 2) ? yacc[i][mt].z : yacc[i][mt].w;
          y[xbase + ((size_t)co << 16) + (size_t)((ty0 + row) * WW + tx0 + l15)] = v;
        }
      }
    }
  }
}

extern "C" void kernel_launch(void* const* d_in, const int* in_sizes, int n_in,
                              void* d_out, int out_size, void* d_ws, size_t ws_size,
                              hipStream_t stream) {
  const float* x      = (const float*)d_in[0];
  const float* time   = (const float*)d_in[1];
  const float* time_w = (const float*)d_in[2];
  const float* time_b = (const float*)d_in[3];
  const float* gw1    = (const float*)d_in[4];
  const float* gb1    = (const float*)d_in[5];
  const float* gw2    = (const float*)d_in[6];
  const float* gb2    = (const float*)d_in[7];
  const float* w1     = (const float*)d_in[8];
  const float* w2     = (const float*)d_in[9];
  float* out = (float*)d_out;
  float* ws  = (float*)d_ws;
  unsigned short* wt1 = (unsigned short*)((char*)d_ws + WT1_OFF);
  unsigned short* wt2 = (unsigned short*)((char*)d_ws + WT2_OFF);

  hipLaunchKernelGGL(pool_kernel, dim3(BB * CCH), dim3(256), 0, stream, x, ws);
  hipLaunchKernelGGL(gate_kernel, dim3(1), dim3(128), 0, stream,
                     time, time_w, time_b, gw1, gb1, gw2, gb2,
                     ws, out + (size_t)(out_size - 1));
  hipLaunchKernelGGL(wxform_kernel, dim3(756), dim3(256), 0, stream, w1, w2, wt1, wt2);
  hipLaunchKernelGGL(conv_kernel, dim3(512, BB), dim3(256), 0, stream,
                     x, wt1, wt2, ws + WS_GATES, out);
}

// Round 8
// 243.207 us; speedup vs baseline: 3.5734x; 1.0346x over previous
//
#include <hip/hip_runtime.h>
#include <hip/hip_bf16.h>
#include <math.h>

#define BB 8
#define CCH 36
#define HH 256
#define WW 256
#define EE 6
#define TDIM 32
#define HID 72
// ws layout: floats [0,288) avg; [288,576) max; [576,624) gates.
// bytes: wt1 frags at 4096 (360 x 1024B); wt2 frags at 372736 (378 x 1024B).
#define WS_GATES (BB*CCH*2)
#define WT1_OFF 4096
#define WT2_OFF (4096 + 368640)

// conv geometry: 16w x 8t output tile, 4 waves
#define TW 16
#define TH 8
#define XR 12
#define XC 20
#define TR 10
#define TC 18

typedef __attribute__((ext_vector_type(8))) short bf16x8;
typedef __attribute__((ext_vector_type(4))) float f32x4;

static __device__ __forceinline__ unsigned short f2bf(float f) {
  __hip_bfloat16 h = __float2bfloat16(f);   // RNE; compiler emits HW cvt
  return *(unsigned short*)&h;
}
// sigmoid-form GELU: x * rcp(1 + exp(-2u)), 2u = x*(1.5958 + 0.07135 x^2).
// No clamp needed: exp->inf => rcp->0 => result 0; exp->0 => result x. |err|~3e-4.
static __device__ __forceinline__ float gelu_fast(float x) {
  float n2u = x * (-1.5957691216f - 0.0713548162f * x * x);
  float r = __builtin_amdgcn_rcpf(1.f + __expf(n2u));
  return x * r;
}

// ---------------- Kernel 1: pool (blocks 0..287) + weight transform (blocks 288..1043) ----
// wt1 frag f = ((e*3+dx)*4+kc)*5+mt; elem = f*512 + lane*8 + j.
//   co = mt*16 + (lane&15); k = kc*32 + (lane>>4)*8 + j; k = dy*40+ci, K=120 (pads ZERO).
// wt2 frag f = ((e*3+dx)*7+kc)*3+mt; k = dy*72+ci, K=216 (pads ZERO).
__global__ __launch_bounds__(256) void poolwx_kernel(const float* __restrict__ x,
                                                     const float* __restrict__ w1,
                                                     const float* __restrict__ w2,
                                                     float* __restrict__ ws,
                                                     unsigned short* __restrict__ wt1,
                                                     unsigned short* __restrict__ wt2) {
  if (blockIdx.x < 288) {
    const int bc = blockIdx.x;
    const float* p = x + (size_t)bc * (HH * WW);
    float s = 0.f, m = -INFINITY;
    for (int i = threadIdx.x; i < (HH * WW) / 4; i += 256) {
      float4 v = ((const float4*)p)[i];
      s += v.x + v.y + v.z + v.w;
      m = fmaxf(m, fmaxf(fmaxf(v.x, v.y), fmaxf(v.z, v.w)));
    }
    for (int off = 32; off; off >>= 1) {
      s += __shfl_down(s, off);
      m = fmaxf(m, __shfl_down(m, off));
    }
    __shared__ float ss[4], sm[4];
    int wid = threadIdx.x >> 6, lane = threadIdx.x & 63;
    if (lane == 0) { ss[wid] = s; sm[wid] = m; }
    __syncthreads();
    if (threadIdx.x == 0) {
      float S = ss[0] + ss[1] + ss[2] + ss[3];
      float M = fmaxf(fmaxf(sm[0], sm[1]), fmaxf(sm[2], sm[3]));
      ws[bc] = S * (1.f / (HH * WW));
      ws[BB * CCH + bc] = M;
    }
    return;
  }
  int i = (blockIdx.x - 288) * 256 + threadIdx.x;
  const int n1 = 360 * 512;
  if (i < n1) {
    int j = i & 7;
    int lane = (i >> 3) & 63;
    int f = i >> 9;
    int mt = f % 5;  f /= 5;
    int kc = f % 4;  f /= 4;
    int dx = f % 3;  int e = f / 3;
    int co = mt * 16 + (lane & 15);
    int k = kc * 32 + (lane >> 4) * 8 + j;
    int dy = k / 40, ci = k % 40;
    float v = 0.f;
    if (co < HID && k < 120 && ci < CCH)
      v = w1[(((size_t)(e * HID + co) * CCH + ci) * 3 + dy) * 3 + dx];
    wt1[i] = f2bf(v);
  }
  const int n2 = 378 * 512;
  if (i < n2) {
    int j = i & 7;
    int lane = (i >> 3) & 63;
    int f = i >> 9;
    int mt = f % 3;  f /= 3;
    int kc = f % 7;  f /= 7;
    int dx = f % 3;  int e = f / 3;
    int co = mt * 16 + (lane & 15);
    int k = kc * 32 + (lane >> 4) * 8 + j;
    int dy = k / 72, ci = k % 72;
    float v = 0.f;
    if (co < CCH && k < 216)
      v = w2[(((size_t)(e * CCH + co) * HID + ci) * 3 + dy) * 3 + dx];
    wt2[i] = f2bf(v);
  }
}

// ---------------- Kernel 2: gating MLP + top-2 + loss ----------------
__global__ void gate_kernel(const float* __restrict__ time,
                            const float* __restrict__ time_w,
                            const float* __restrict__ time_b,
                            const float* __restrict__ w1, const float* __restrict__ b1,
                            const float* __restrict__ w2, const float* __restrict__ b2,
                            float* __restrict__ ws, float* __restrict__ loss_out) {
  __shared__ float v[BB * HID];
  __shared__ float h[BB * HID];
  __shared__ float logits[BB * EE];
  const int t = threadIdx.x;
  const float* avg = ws;
  const float* mx = ws + BB * CCH;
  for (int i = t; i < BB * HID; i += blockDim.x) {
    int b = i / HID, c = i % HID;
    float base = (c < CCH) ? avg[b * CCH + c] : mx[b * CCH + (c - CCH)];
    float acc = time_b[c];
    for (int k = 0; k < TDIM; k++) acc += time[b * TDIM + k] * time_w[k * HID + c];
    v[i] = base + acc;
  }
  __syncthreads();
  for (int i = t; i < BB * HID; i += blockDim.x) {
    int b = i / HID, c = i % HID;
    float acc = b1[c];
    for (int k = 0; k < HID; k++) acc += v[b * HID + k] * w1[k * HID + c];
    h[i] = acc > 0.f ? acc : 0.01f * acc;
  }
  __syncthreads();
  for (int i = t; i < BB * EE; i += blockDim.x) {
    int b = i / EE, e = i % EE;
    float acc = b2[e];
    for (int k = 0; k < HID; k++) acc += h[b * HID + k] * w2[k * EE + e];
    logits[i] = acc;
  }
  __syncthreads();
  if (t == 0) {
    float imp[EE], ld[EE];
    for (int e = 0; e < EE; e++) { imp[e] = 0.f; ld[e] = 0.f; }
    for (int b = 0; b < BB; b++) {
      int i1 = -1, i2 = -1;
      float v1 = -1e30f, v2 = -1e30f;
      for (int e = 0; e < EE; e++) {
        float lv = logits[b * EE + e];
        if (lv > v1) { v2 = v1; i2 = i1; v1 = lv; i1 = e; }
        else if (lv > v2) { v2 = lv; i2 = e; }
      }
      float e2 = expf(v2 - v1);
      float g1 = 1.f / (1.f + e2), g2 = e2 / (1.f + e2);
      for (int e = 0; e < EE; e++) ws[WS_GATES + b * EE + e] = 0.f;
      ws[WS_GATES + b * EE + i1] = g1;
      ws[WS_GATES + b * EE + i2] = g2;
      imp[i1] += g1; imp[i2] += g2;
      ld[i1] += 1.f; ld[i2] += 1.f;
    }
    float loss = 0.f;
    {
      float m = 0.f; for (int e = 0; e < EE; e++) m += imp[e]; m /= EE;
      float var = 0.f; for (int e = 0; e < EE; e++) { float d = imp[e] - m; var += d * d; }
      var /= (EE - 1);
      loss += var / (m * m + 1e-10f);
      m = 0.f; for (int e = 0; e < EE; e++) m += ld[e]; m /= EE;
      var = 0.f; for (int e = 0; e < EE; e++) { float d = ld[e] - m; var += d * d; }
      var /= (EE - 1);
      loss += var / (m * m + 1e-10f);
    }
    loss_out[0] = 0.01f * loss;
  }
}

// ---------------- Kernel 3: fused MFMA conv1+GELU+conv2 ----------------
// Tile 16x8, 4 waves. Chunked LDS layouts (16-B lane stride, bank-optimal):
//   xs[c8][xr][xc][8ci] : c8<5, 3840B/chunk, rows 320B -> 19200 B
//   ts[c9][tr][tc][8co] : c9<9, 2880B/chunk, rows 288B -> 25920 B
// Weight A-fragments stream from global (fragment order) with reg double-buffer.
// Invalid K-chunks clamp to offset 0: their WEIGHT rows are zero => junk*0=0.
__global__ __launch_bounds__(256, 3) void conv_kernel(
    const float* __restrict__ x,
    const unsigned short* __restrict__ wt1,
    const unsigned short* __restrict__ wt2,
    const float* __restrict__ wsg,
    float* __restrict__ y) {
  __shared__ __align__(16) char lds[45120];
  char* xsB = lds;                 // 19200 B
  char* tsB = lds + 19200;         // 25920 B

  const int tid = threadIdx.x;
  const int w = tid >> 6;
  const int lane = tid & 63;
  const int l15 = lane & 15;
  const int kl = lane >> 4;
  const int b = blockIdx.y;
  // XCD-chunked swizzle: each XCD gets a contiguous 4-tile-row band.
  const int tileId = (blockIdx.x & 7) * 64 + (blockIdx.x >> 3);
  const int tx0 = (tileId & 15) * TW;
  const int ty0 = (tileId >> 4) * TH;
  const size_t xbase = (size_t)b * (CCH * HH * WW);

  // active experts
  int eids[2] = {0, 0};
  float gvals[2] = {0.f, 0.f};
  int ne = 0;
  for (int e = 0; e < EE; e++) {
    float g = wsg[b * EE + e];
    if (g != 0.f && ne < 2) { eids[ne] = e; gvals[ne] = g; ne++; }
  }

  // ---- stage x tile: thread owns (xr,xc); 5 chunks of 8 ci, 16-B writes ----
  if (tid < XR * XC) {
    const int xr = tid / XC, xc = tid - (tid / XC) * XC;
    const int gy = ty0 - 2 + xr, gx = tx0 - 2 + xc;
    const bool valid = ((unsigned)gy < (unsigned)HH) && ((unsigned)gx < (unsigned)WW);
    const float* xp = x + xbase + (size_t)(gy * WW + gx);
    char* dstb = xsB + (xr * XC + xc) * 16;
#pragma unroll
    for (int c8 = 0; c8 < 5; c8++) {
      unsigned int pk[4];
#pragma unroll
      for (int q = 0; q < 4; q++) {
        int ci0 = c8 * 8 + q * 2, ci1 = ci0 + 1;
        float v0 = (ci0 < CCH && valid) ? xp[(size_t)ci0 << 16] : 0.f;
        float v1 = (ci1 < CCH && valid) ? xp[(size_t)ci1 << 16] : 0.f;
        pk[q] = (unsigned)f2bf(v0) | ((unsigned)f2bf(v1) << 16);
      }
      *(uint4*)(dstb + c8 * 3840) = make_uint4(pk[0], pk[1], pk[2], pk[3]);
    }
  }

  // ---- per-lane K-chunk byte offsets (clamped; zero-weight rows cover invalid) ----
  int xkc[4];
#pragma unroll
  for (int kc = 0; kc < 4; kc++) {
    int k0 = kc * 32 + kl * 8;
    int d = (k0 >= 80) ? 2 : (k0 >= 40 ? 1 : 0);
    int ci0 = k0 - 40 * d;
    xkc[kc] = (k0 < 120) ? ((ci0 >> 3) * 3840 + d * 320) : 0;
  }
  int tkc[7];
#pragma unroll
  for (int kc = 0; kc < 7; kc++) {
    int k0 = kc * 32 + kl * 8;
    int d = (k0 >= 144) ? 2 : (k0 >= 72 ? 1 : 0);
    int ci0 = k0 - 72 * d;
    tkc[kc] = (k0 < 216) ? ((ci0 >> 3) * 2880 + d * 288) : 0;
  }

  // ---- conv1 pixel coords: T grid 10x18=180 px, 12 slots; wave w owns w,w+4,w+8 ----
  int pbase1[3], tsoff[3], vimg[3], pst[3];
#pragma unroll
  for (int i = 0; i < 3; i++) {
    int p = (w + 4 * i) * 16 + l15;
    int tr = p / TC, tc = p - tr * TC;
    pst[i] = (p < TR * TC) ? 1 : 0;
    int trc = tr < (TR - 1) ? tr : (TR - 1);
    pbase1[i] = trc * 320 + tc * 16;
    tsoff[i] = trc * 288 + tc * 16;
    int gy = ty0 - 1 + tr, gx = tx0 - 1 + tc;
    vimg[i] = (pst[i] && (unsigned)gy < (unsigned)HH && (unsigned)gx < (unsigned)WW) ? 1 : 0;
  }
  // conv2: 8 rows; wave w owns rows w, w+4. col = l15.
  int pbase2[2];
#pragma unroll
  for (int i = 0; i < 2; i++) pbase2[i] = (w + 4 * i) * 288 + l15 * 16;

  const unsigned short* w1lane = wt1 + lane * 8;
  const unsigned short* w2lane = wt2 + lane * 8;

  f32x4 yacc[2][3];
#pragma unroll
  for (int i = 0; i < 2; i++)
#pragma unroll
    for (int mt = 0; mt < 3; mt++) yacc[i][mt] = (f32x4){0.f, 0.f, 0.f, 0.f};

  __syncthreads();

#pragma unroll
  for (int ei = 0; ei < 2; ei++) {
    if (ei >= ne) break;
    const float gv = gvals[ei];
    const unsigned short* w1p = w1lane + eids[ei] * 30720;   // 3*80*128
    const unsigned short* w2p = w2lane + eids[ei] * 32256;   // 3*48*224

    // ================= conv1: 12 steps (dx*4+kc), A double-buffered =================
    f32x4 acc[3][5];
#pragma unroll
    for (int i = 0; i < 3; i++)
#pragma unroll
      for (int mt = 0; mt < 5; mt++) acc[i][mt] = (f32x4){0.f, 0.f, 0.f, 0.f};

    bf16x8 aA[5], aB[5];
#pragma unroll
    for (int mt = 0; mt < 5; mt++) aA[mt] = *(const bf16x8*)(w1p + mt * 512);

#pragma unroll
    for (int jj = 0; jj < 12; jj++) {
      if (jj < 11) {
#pragma unroll
        for (int mt = 0; mt < 5; mt++)
          ((jj & 1) ? aA : aB)[mt] = *(const bf16x8*)(w1p + ((jj + 1) * 5 + mt) * 512);
      }
      const int kc = jj & 3;
      const int dxo = (jj >> 2) * 16;
      bf16x8 bv[3];
#pragma unroll
      for (int i = 0; i < 3; i++)
        bv[i] = *(const bf16x8*)(xsB + (pbase1[i] + xkc[kc] + dxo));
      __builtin_amdgcn_s_setprio(1);
#pragma unroll
      for (int mt = 0; mt < 5; mt++) {
        bf16x8 av = ((jj & 1) ? aB : aA)[mt];
#pragma unroll
        for (int i = 0; i < 3; i++)
          acc[i][mt] = __builtin_amdgcn_mfma_f32_16x16x32_bf16(av, bv[i], acc[i][mt], 0, 0, 0);
      }
      __builtin_amdgcn_s_setprio(0);
    }

    // preload conv2 first frag-group (latency hides under GELU/store)
    bf16x8 cA[3], cB[3];
#pragma unroll
    for (int mt = 0; mt < 3; mt++) cA[mt] = *(const bf16x8*)(w2p + mt * 512);

    // ---- GELU + store T (8-B packed, exact 0 outside image) ----
#pragma unroll
    for (int i = 0; i < 3; i++) {
      if (pst[i]) {
#pragma unroll
        for (int mt = 0; mt < 5; mt++) {
          int co0 = mt * 16 + kl * 4;
          if (co0 < HID) {
            float v0 = vimg[i] ? gelu_fast(acc[i][mt].x) : 0.f;
            float v1 = vimg[i] ? gelu_fast(acc[i][mt].y) : 0.f;
            float v2 = vimg[i] ? gelu_fast(acc[i][mt].z) : 0.f;
            float v3 = vimg[i] ? gelu_fast(acc[i][mt].w) : 0.f;
            unsigned int lo = (unsigned)f2bf(v0) | ((unsigned)f2bf(v1) << 16);
            unsigned int hi = (unsigned)f2bf(v2) | ((unsigned)f2bf(v3) << 16);
            int addr = (co0 >> 3) * 2880 + tsoff[i] + (co0 & 7) * 2;
            *(uint2*)(tsB + addr) = make_uint2(lo, hi);
          }
        }
      }
    }
    __syncthreads();

    // ================= conv2: 21 steps (dx*7+kc), A double-buffered =================
    f32x4 acc2[2][3];
#pragma unroll
    for (int i = 0; i < 2; i++)
#pragma unroll
      for (int mt = 0; mt < 3; mt++) acc2[i][mt] = (f32x4){0.f, 0.f, 0.f, 0.f};

#pragma unroll
    for (int jj = 0; jj < 21; jj++) {
      if (jj < 20) {
#pragma unroll
        for (int mt = 0; mt < 3; mt++)
          ((jj & 1) ? cA : cB)[mt] = *(const bf16x8*)(w2p + ((jj + 1) * 3 + mt) * 512);
      }
      const int kc = jj % 7;
      const int dxo = (jj / 7) * 16;
      bf16x8 bv[2];
#pragma unroll
      for (int i = 0; i < 2; i++)
        bv[i] = *(const bf16x8*)(tsB + (pbase2[i] + tkc[kc] + dxo));
      __builtin_amdgcn_s_setprio(1);
#pragma unroll
      for (int mt = 0; mt < 3; mt++) {
        bf16x8 av = ((jj & 1) ? cB : cA)[mt];
#pragma unroll
        for (int i = 0; i < 2; i++)
          acc2[i][mt] = __builtin_amdgcn_mfma_f32_16x16x32_bf16(av, bv[i], acc2[i][mt], 0, 0, 0);
      }
      __builtin_amdgcn_s_setprio(0);
    }
#pragma unroll
    for (int i = 0; i < 2; i++)
#pragma unroll
      for (int mt = 0; mt < 3; mt++) yacc[i][mt] += gv * acc2[i][mt];
    __syncthreads();   // ts free for next expert
  }

  // ---- store y (f32) ----
#pragma unroll
  for (int i = 0; i < 2; i++) {
    int row = w + 4 * i;
#pragma unroll
    for (int mt = 0; mt < 3; mt++) {
#pragma unroll
      for (int r = 0; r < 4; r++) {
        int co = mt * 16 + kl * 4 + r;
        if (co < CCH) {
          float v = (r == 0) ? yacc[i][mt].x : (r == 1) ? yacc[i][mt].y
                  : (r == 2) ? yacc[i][mt].z : yacc[i][mt].w;
          y[xbase + ((size_t)co << 16) + (size_t)((ty0 + row) * WW + tx0 + l15)] = v;
        }
      }
    }
  }
}

extern "C" void kernel_launch(void* const* d_in, const int* in_sizes, int n_in,
                              void* d_out, int out_size, void* d_ws, size_t ws_size,
                              hipStream_t stream) {
  const float* x      = (const float*)d_in[0];
  const float* time   = (const float*)d_in[1];
  const float* time_w = (const float*)d_in[2];
  const float* time_b = (const float*)d_in[3];
  const float* gw1    = (const float*)d_in[4];
  const float* gb1    = (const float*)d_in[5];
  const float* gw2    = (const float*)d_in[6];
  const float* gb2    = (const float*)d_in[7];
  const float* w1     = (const float*)d_in[8];
  const float* w2     = (const float*)d_in[9];
  float* out = (float*)d_out;
  float* ws  = (float*)d_ws;
  unsigned short* wt1 = (unsigned short*)((char*)d_ws + WT1_OFF);
  unsigned short* wt2 = (unsigned short*)((char*)d_ws + WT2_OFF);

  hipLaunchKernelGGL(poolwx_kernel, dim3(288 + 756), dim3(256), 0, stream,
                     x, w1, w2, ws, wt1, wt2);
  hipLaunchKernelGGL(gate_kernel, dim3(1), dim3(128), 0, stream,
                     time, time_w, time_b, gw1, gb1, gw2, gb2,
                     ws, out + (size_t)(out_size - 1));
  hipLaunchKernelGGL(conv_kernel, dim3(512, BB), dim3(256), 0, stream,
                     x, wt1, wt2, ws + WS_GATES, out);
}

// Round 9
// 238.726 us; speedup vs baseline: 3.6405x; 1.0188x over previous
//
#include <hip/hip_runtime.h>
#include <hip/hip_bf16.h>
#include <math.h>

#define BB 8
#define CCH 36
#define HH 256
#define WW 256
#define EE 6
#define TDIM 32
#define HID 72
// ws layout: floats [0,288) avg; [288,576) max; [576,624) gates.
// bytes: wt1 frags at 4096 (360 x 1024B); wt2 frags at 372736 (378 x 1024B).
#define WS_GATES (BB*CCH*2)
#define WT1_OFF 4096
#define WT2_OFF (4096 + 368640)

// conv geometry: 16w x 8t output tile, 4 waves
#define TW 16
#define TH 8
#define XR 12
#define XC 20
#define TR 10
#define TC 18

typedef __attribute__((ext_vector_type(8))) short bf16x8;
typedef __attribute__((ext_vector_type(4))) float f32x4;

static __device__ __forceinline__ unsigned short f2bf(float f) {
  __hip_bfloat16 h = __float2bfloat16(f);   // RNE; compiler emits HW cvt
  return *(unsigned short*)&h;
}
// sigmoid-form GELU: x * rcp(1 + exp(-2u)), 2u = x*(1.5958 + 0.07135 x^2).
// No clamp needed: exp->inf => rcp->0 => result 0; exp->0 => result x. |err|~3e-4.
static __device__ __forceinline__ float gelu_fast(float x) {
  float n2u = x * (-1.5957691216f - 0.0713548162f * x * x);
  float r = __builtin_amdgcn_rcpf(1.f + __expf(n2u));
  return x * r;
}

// ---------------- Kernel 1: pool (blocks 0..287) + weight transform (288..1043) ----
// wt1 frag f = ((e*3+dx)*4+kc)*5+mt; elem = f*512 + lane*8 + j.
//   co = mt*16 + (lane&15); k = kc*32 + (lane>>4)*8 + j; k = dy*40+ci, K=120 (pads ZERO).
// wt2 frag f = ((e*3+dx)*7+kc)*3+mt; k = dy*72+ci, K=216 (pads ZERO).
__global__ __launch_bounds__(256) void poolwx_kernel(const float* __restrict__ x,
                                                     const float* __restrict__ w1,
                                                     const float* __restrict__ w2,
                                                     float* __restrict__ ws,
                                                     unsigned short* __restrict__ wt1,
                                                     unsigned short* __restrict__ wt2) {
  if (blockIdx.x < 288) {
    const int bc = blockIdx.x;
    const float* p = x + (size_t)bc * (HH * WW);
    float s = 0.f, m = -INFINITY;
    for (int i = threadIdx.x; i < (HH * WW) / 4; i += 256) {
      float4 v = ((const float4*)p)[i];
      s += v.x + v.y + v.z + v.w;
      m = fmaxf(m, fmaxf(fmaxf(v.x, v.y), fmaxf(v.z, v.w)));
    }
    for (int off = 32; off; off >>= 1) {
      s += __shfl_down(s, off);
      m = fmaxf(m, __shfl_down(m, off));
    }
    __shared__ float ss[4], sm[4];
    int wid = threadIdx.x >> 6, lane = threadIdx.x & 63;
    if (lane == 0) { ss[wid] = s; sm[wid] = m; }
    __syncthreads();
    if (threadIdx.x == 0) {
      float S = ss[0] + ss[1] + ss[2] + ss[3];
      float M = fmaxf(fmaxf(sm[0], sm[1]), fmaxf(sm[2], sm[3]));
      ws[bc] = S * (1.f / (HH * WW));
      ws[BB * CCH + bc] = M;
    }
    return;
  }
  int i = (blockIdx.x - 288) * 256 + threadIdx.x;
  const int n1 = 360 * 512;
  if (i < n1) {
    int j = i & 7;
    int lane = (i >> 3) & 63;
    int f = i >> 9;
    int mt = f % 5;  f /= 5;
    int kc = f % 4;  f /= 4;
    int dx = f % 3;  int e = f / 3;
    int co = mt * 16 + (lane & 15);
    int k = kc * 32 + (lane >> 4) * 8 + j;
    int dy = k / 40, ci = k % 40;
    float v = 0.f;
    if (co < HID && k < 120 && ci < CCH)
      v = w1[(((size_t)(e * HID + co) * CCH + ci) * 3 + dy) * 3 + dx];
    wt1[i] = f2bf(v);
  }
  const int n2 = 378 * 512;
  if (i < n2) {
    int j = i & 7;
    int lane = (i >> 3) & 63;
    int f = i >> 9;
    int mt = f % 3;  f /= 3;
    int kc = f % 7;  f /= 7;
    int dx = f % 3;  int e = f / 3;
    int co = mt * 16 + (lane & 15);
    int k = kc * 32 + (lane >> 4) * 8 + j;
    int dy = k / 72, ci = k % 72;
    float v = 0.f;
    if (co < CCH && k < 216)
      v = w2[(((size_t)(e * CCH + co) * HID + ci) * 3 + dy) * 3 + dx];
    wt2[i] = f2bf(v);
  }
}

// ---------------- Kernel 2: gating MLP + top-2 + loss ----------------
__global__ void gate_kernel(const float* __restrict__ time,
                            const float* __restrict__ time_w,
                            const float* __restrict__ time_b,
                            const float* __restrict__ w1, const float* __restrict__ b1,
                            const float* __restrict__ w2, const float* __restrict__ b2,
                            float* __restrict__ ws, float* __restrict__ loss_out) {
  __shared__ float v[BB * HID];
  __shared__ float h[BB * HID];
  __shared__ float logits[BB * EE];
  const int t = threadIdx.x;
  const float* avg = ws;
  const float* mx = ws + BB * CCH;
  for (int i = t; i < BB * HID; i += blockDim.x) {
    int b = i / HID, c = i % HID;
    float base = (c < CCH) ? avg[b * CCH + c] : mx[b * CCH + (c - CCH)];
    float acc = time_b[c];
    for (int k = 0; k < TDIM; k++) acc += time[b * TDIM + k] * time_w[k * HID + c];
    v[i] = base + acc;
  }
  __syncthreads();
  for (int i = t; i < BB * HID; i += blockDim.x) {
    int b = i / HID, c = i % HID;
    float acc = b1[c];
    for (int k = 0; k < HID; k++) acc += v[b * HID + k] * w1[k * HID + c];
    h[i] = acc > 0.f ? acc : 0.01f * acc;
  }
  __syncthreads();
  for (int i = t; i < BB * EE; i += blockDim.x) {
    int b = i / EE, e = i % EE;
    float acc = b2[e];
    for (int k = 0; k < HID; k++) acc += h[b * HID + k] * w2[k * EE + e];
    logits[i] = acc;
  }
  __syncthreads();
  if (t == 0) {
    float imp[EE], ld[EE];
    for (int e = 0; e < EE; e++) { imp[e] = 0.f; ld[e] = 0.f; }
    for (int b = 0; b < BB; b++) {
      int i1 = -1, i2 = -1;
      float v1 = -1e30f, v2 = -1e30f;
      for (int e = 0; e < EE; e++) {
        float lv = logits[b * EE + e];
        if (lv > v1) { v2 = v1; i2 = i1; v1 = lv; i1 = e; }
        else if (lv > v2) { v2 = lv; i2 = e; }
      }
      float e2 = expf(v2 - v1);
      float g1 = 1.f / (1.f + e2), g2 = e2 / (1.f + e2);
      for (int e = 0; e < EE; e++) ws[WS_GATES + b * EE + e] = 0.f;
      ws[WS_GATES + b * EE + i1] = g1;
      ws[WS_GATES + b * EE + i2] = g2;
      imp[i1] += g1; imp[i2] += g2;
      ld[i1] += 1.f; ld[i2] += 1.f;
    }
    float loss = 0.f;
    {
      float m = 0.f; for (int e = 0; e < EE; e++) m += imp[e]; m /= EE;
      float var = 0.f; for (int e = 0; e < EE; e++) { float d = imp[e] - m; var += d * d; }
      var /= (EE - 1);
      loss += var / (m * m + 1e-10f);
      m = 0.f; for (int e = 0; e < EE; e++) m += ld[e]; m /= EE;
      var = 0.f; for (int e = 0; e < EE; e++) { float d = ld[e] - m; var += d * d; }
      var /= (EE - 1);
      loss += var / (m * m + 1e-10f);
    }
    loss_out[0] = 0.01f * loss;
  }
}

// ---------------- Kernel 3: fused MFMA conv1+GELU+conv2 ----------------
// Tile 16x8, 4 waves. Chunked LDS (16-B lane stride):
//   xs[c8<5][xr][xc][8ci] 19200 B; ts[c9<9][tr][tc][8co] 25920 B + 2880 B junk pad
//   (GELU rows co 72..79 write into the pad -> no predicate needed).
// Weight bases are SGPR (readfirstlane'd expert ids) -> saddr loads, one lane*16
// voffset. LDS inner-loop addresses are precomputed base regs + offset immediates.
__global__ __launch_bounds__(256, 3) void conv_kernel(
    const float* __restrict__ x,
    const unsigned short* __restrict__ wt1,
    const unsigned short* __restrict__ wt2,
    const float* __restrict__ wsg,
    float* __restrict__ y) {
  __shared__ __align__(16) char lds[48000];   // 19200 xs + 25920 ts + 2880 pad
  char* xsB = lds;
  char* tsB = lds + 19200;

  const int tid = threadIdx.x;
  const int w = tid >> 6;
  const int lane = tid & 63;
  const int l15 = lane & 15;
  const int kl = lane >> 4;
  const int b = blockIdx.y;
  // XCD-chunked swizzle: each XCD gets a contiguous 4-tile-row band.
  const int tileId = (blockIdx.x & 7) * 64 + (blockIdx.x >> 3);
  const int tx0 = (tileId & 15) * TW;
  const int ty0 = (tileId >> 4) * TH;
  const size_t xbase = (size_t)b * (CCH * HH * WW);

  // active experts -> wave-uniform scalars
  int eids[2] = {0, 0};
  float gvals[2] = {0.f, 0.f};
  int ne = 0;
  for (int e = 0; e < EE; e++) {
    float g = wsg[b * EE + e];
    if (g != 0.f && ne < 2) { eids[ne] = e; gvals[ne] = g; ne++; }
  }
  ne = __builtin_amdgcn_readfirstlane(ne);
  const int e0 = __builtin_amdgcn_readfirstlane(eids[0]);
  const int e1 = __builtin_amdgcn_readfirstlane(eids[1]);
  const float g0 = __int_as_float(__builtin_amdgcn_readfirstlane(__float_as_int(gvals[0])));
  const float g1 = __int_as_float(__builtin_amdgcn_readfirstlane(__float_as_int(gvals[1])));

  // ---- stage x tile: thread owns (xr,xc); 5 chunks of 8 ci, 16-B writes ----
  if (tid < XR * XC) {
    const int xr = tid / XC, xc = tid - (tid / XC) * XC;
    const int gy = ty0 - 2 + xr, gx = tx0 - 2 + xc;
    const bool valid = ((unsigned)gy < (unsigned)HH) && ((unsigned)gx < (unsigned)WW);
    const float* xp = x + xbase + (size_t)(gy * WW + gx);
    char* dstb = xsB + (xr * XC + xc) * 16;
#pragma unroll
    for (int c8 = 0; c8 < 5; c8++) {
      unsigned int pk[4];
#pragma unroll
      for (int q = 0; q < 4; q++) {
        int ci0 = c8 * 8 + q * 2, ci1 = ci0 + 1;
        float v0 = (ci0 < CCH && valid) ? xp[(size_t)ci0 << 16] : 0.f;
        float v1 = (ci1 < CCH && valid) ? xp[(size_t)ci1 << 16] : 0.f;
        pk[q] = (unsigned)f2bf(v0) | ((unsigned)f2bf(v1) << 16);
      }
      *(uint4*)(dstb + c8 * 3840) = make_uint4(pk[0], pk[1], pk[2], pk[3]);
    }
  }

  // ---- conv1 pixel coords: T grid 10x18=180 px, 12 slots; wave w owns w,w+4,w+8 ----
  int vimg[3], pst[3], tsoff[3], pb1[3];
#pragma unroll
  for (int i = 0; i < 3; i++) {
    int p = (w + 4 * i) * 16 + l15;
    int tr = p / TC, tc = p - tr * TC;
    pst[i] = (p < TR * TC) ? 1 : 0;
    int trc = tr < (TR - 1) ? tr : (TR - 1);
    pb1[i] = trc * 320 + tc * 16;
    tsoff[i] = trc * 288 + tc * 16;
    int gy = ty0 - 1 + tr, gx = tx0 - 1 + tc;
    vimg[i] = (pst[i] && (unsigned)gy < (unsigned)HH && (unsigned)gx < (unsigned)WW) ? 1 : 0;
  }
  // precomputed conv1 LDS read bases: b1[kc][i] = pb1[i] + xkc[kc]
  int b1a[4][3];
#pragma unroll
  for (int kc = 0; kc < 4; kc++) {
    int k0 = kc * 32 + kl * 8;
    int d = (k0 >= 80) ? 2 : (k0 >= 40 ? 1 : 0);
    int xkc = (k0 < 120) ? (((k0 - 40 * d) >> 3) * 3840 + d * 320) : 0;
#pragma unroll
    for (int i = 0; i < 3; i++) b1a[kc][i] = pb1[i] + xkc;
  }
  // GELU store base: addr = tsStore[i] + mt*5760  (co0=mt*16+kl*4)
  int tsStore[3];
#pragma unroll
  for (int i = 0; i < 3; i++) tsStore[i] = tsoff[i] + (kl >> 1) * 2880 + (kl & 1) * 8;

  // conv2: 8 rows; wave w owns rows w, w+4; col = l15. b2[kc][i] precomputed.
  int b2a[7][2];
#pragma unroll
  for (int kc = 0; kc < 7; kc++) {
    int k0 = kc * 32 + kl * 8;
    int d = (k0 >= 144) ? 2 : (k0 >= 72 ? 1 : 0);
    int tkc = (k0 < 216) ? (((k0 - 72 * d) >> 3) * 2880 + d * 288) : 0;
#pragma unroll
    for (int i = 0; i < 2; i++) b2a[kc][i] = (w + 4 * i) * 288 + l15 * 16 + tkc;
  }

  const int lob = lane * 8;   // lane element offset (16 B) for weight fragments

  f32x4 yacc[2][3];
#pragma unroll
  for (int i = 0; i < 2; i++)
#pragma unroll
    for (int mt = 0; mt < 3; mt++) yacc[i][mt] = (f32x4){0.f, 0.f, 0.f, 0.f};

  __syncthreads();

#pragma unroll
  for (int ei = 0; ei < 2; ei++) {
    if (ei >= ne) break;
    const float gv = ei ? g1 : g0;
    const unsigned short* w1p = wt1 + (ei ? e1 : e0) * 30720;   // SGPR base
    const unsigned short* w2p = wt2 + (ei ? e1 : e0) * 32256;   // SGPR base

    // ================= conv1: 12 steps (dx*4+kc), A double-buffered =================
    f32x4 acc[3][5];
#pragma unroll
    for (int i = 0; i < 3; i++)
#pragma unroll
      for (int mt = 0; mt < 5; mt++) acc[i][mt] = (f32x4){0.f, 0.f, 0.f, 0.f};

    bf16x8 aA[5], aB[5];
#pragma unroll
    for (int mt = 0; mt < 5; mt++) aA[mt] = *(const bf16x8*)(w1p + mt * 512 + lob);

#pragma unroll
    for (int jj = 0; jj < 12; jj++) {
      if (jj < 11) {
#pragma unroll
        for (int mt = 0; mt < 5; mt++)
          ((jj & 1) ? aA : aB)[mt] = *(const bf16x8*)(w1p + ((jj + 1) * 5 + mt) * 512 + lob);
      }
      const int kc = jj & 3;
      const int dxo = (jj >> 2) * 16;   // ds_read offset immediate
      bf16x8 bv[3];
#pragma unroll
      for (int i = 0; i < 3; i++)
        bv[i] = *(const bf16x8*)(xsB + b1a[kc][i] + dxo);
      __builtin_amdgcn_s_setprio(1);
#pragma unroll
      for (int mt = 0; mt < 5; mt++) {
        bf16x8 av = ((jj & 1) ? aB : aA)[mt];
#pragma unroll
        for (int i = 0; i < 3; i++)
          acc[i][mt] = __builtin_amdgcn_mfma_f32_16x16x32_bf16(av, bv[i], acc[i][mt], 0, 0, 0);
      }
      __builtin_amdgcn_s_setprio(0);
    }

    // preload conv2 first frag-group (latency hides under GELU/store)
    bf16x8 cA[3], cB[3];
#pragma unroll
    for (int mt = 0; mt < 3; mt++) cA[mt] = *(const bf16x8*)(w2p + mt * 512 + lob);

    // ---- GELU + store T (8-B packed; co 72..79 land in LDS junk pad) ----
#pragma unroll
    for (int i = 0; i < 3; i++) {
      if (pst[i]) {
#pragma unroll
        for (int mt = 0; mt < 5; mt++) {
          float v0 = vimg[i] ? gelu_fast(acc[i][mt].x) : 0.f;
          float v1 = vimg[i] ? gelu_fast(acc[i][mt].y) : 0.f;
          float v2 = vimg[i] ? gelu_fast(acc[i][mt].z) : 0.f;
          float v3 = vimg[i] ? gelu_fast(acc[i][mt].w) : 0.f;
          unsigned int lo = (unsigned)f2bf(v0) | ((unsigned)f2bf(v1) << 16);
          unsigned int hi = (unsigned)f2bf(v2) | ((unsigned)f2bf(v3) << 16);
          *(uint2*)(tsB + tsStore[i] + mt * 5760) = make_uint2(lo, hi);
        }
      }
    }
    __syncthreads();

    // ================= conv2: 21 steps (dx*7+kc), A double-buffered =================
    f32x4 acc2[2][3];
#pragma unroll
    for (int i = 0; i < 2; i++)
#pragma unroll
      for (int mt = 0; mt < 3; mt++) acc2[i][mt] = (f32x4){0.f, 0.f, 0.f, 0.f};

#pragma unroll
    for (int jj = 0; jj < 21; jj++) {
      if (jj < 20) {
#pragma unroll
        for (int mt = 0; mt < 3; mt++)
          ((jj & 1) ? cA : cB)[mt] = *(const bf16x8*)(w2p + ((jj + 1) * 3 + mt) * 512 + lob);
      }
      const int kc = jj % 7;
      const int dxo = (jj / 7) * 16;   // ds_read offset immediate
      bf16x8 bv[2];
#pragma unroll
      for (int i = 0; i < 2; i++)
        bv[i] = *(const bf16x8*)(tsB + b2a[kc][i] + dxo);
      __builtin_amdgcn_s_setprio(1);
#pragma unroll
      for (int mt = 0; mt < 3; mt++) {
        bf16x8 av = ((jj & 1) ? cB : cA)[mt];
#pragma unroll
        for (int i = 0; i < 2; i++)
          acc2[i][mt] = __builtin_amdgcn_mfma_f32_16x16x32_bf16(av, bv[i], acc2[i][mt], 0, 0, 0);
      }
      __builtin_amdgcn_s_setprio(0);
    }
#pragma unroll
    for (int i = 0; i < 2; i++)
#pragma unroll
      for (int mt = 0; mt < 3; mt++) yacc[i][mt] += gv * acc2[i][mt];
    __syncthreads();   // ts free for next expert
  }

  // ---- store y (f32) ----
#pragma unroll
  for (int i = 0; i < 2; i++) {
    int row = w + 4 * i;
#pragma unroll
    for (int mt = 0; mt < 3; mt++) {
#pragma unroll
      for (int r = 0; r < 4; r++) {
        int co = mt * 16 + kl * 4 + r;
        if (co < CCH) {
          float v = (r == 0) ? yacc[i][mt].x : (r == 1) ? yacc[i][mt].y
                  : (r == 2) ? yacc[i][mt].z : yacc[i][mt].w;
          y[xbase + ((size_t)co << 16) + (size_t)((ty0 + row) * WW + tx0 + l15)] = v;
        }
      }
    }
  }
}

extern "C" void kernel_launch(void* const* d_in, const int* in_sizes, int n_in,
                              void* d_out, int out_size, void* d_ws, size_t ws_size,
                              hipStream_t stream) {
  const float* x      = (const float*)d_in[0];
  const float* time   = (const float*)d_in[1];
  const float* time_w = (const float*)d_in[2];
  const float* time_b = (const float*)d_in[3];
  const float* gw1    = (const float*)d_in[4];
  const float* gb1    = (const float*)d_in[5];
  const float* gw2    = (const float*)d_in[6];
  const float* gb2    = (const float*)d_in[7];
  const float* w1     = (const float*)d_in[8];
  const float* w2     = (const float*)d_in[9];
  float* out = (float*)d_out;
  float* ws  = (float*)d_ws;
  unsigned short* wt1 = (unsigned short*)((char*)d_ws + WT1_OFF);
  unsigned short* wt2 = (unsigned short*)((char*)d_ws + WT2_OFF);

  hipLaunchKernelGGL(poolwx_kernel, dim3(288 + 756), dim3(256), 0, stream,
                     x, w1, w2, ws, wt1, wt2);
  hipLaunchKernelGGL(gate_kernel, dim3(1), dim3(128), 0, stream,
                     time, time_w, time_b, gw1, gb1, gw2, gb2,
                     ws, out + (size_t)(out_size - 1));
  hipLaunchKernelGGL(conv_kernel, dim3(512, BB), dim3(256), 0, stream,
                     x, wt1, wt2, ws + WS_GATES, out);
}